// Round 1
// baseline (4991.573 us; speedup 1.0000x reference)
//
#include <hip/hip_runtime.h>

#define N_NODES 50000
#define N_EDGES 400000
#define HID 128
#define NUM_GRAPHS 64

// ---------------- embed gather: h = embed[z] ----------------
__global__ void k_embed(const int* __restrict__ z, const float4* __restrict__ embed4,
                        float4* __restrict__ h4) {
    int idx = blockIdx.x * 256 + threadIdx.x;
    if (idx >= N_NODES * 32) return;
    int node = idx >> 5;
    int c = idx & 31;
    h4[idx] = embed4[(size_t)z[node] * 32 + c];
}

// ---------------- P = h @ w1[0:128], Q = h @ w1[128:256] ----------------
__launch_bounds__(256, 2)
__global__ void k_node_pre(const float* __restrict__ h, const float* __restrict__ w1,
                           float* __restrict__ P, float* __restrict__ Q) {
    __shared__ float sA[HID * 64];   // [k][e] transposed, 32 KB
    __shared__ float sW[64 * 132];   // k-tile of W, padded, 33 KB
    const int tid = threadIdx.x;
    const int n0 = blockIdx.x * 64;
    {
        const int e = tid & 63, qu = tid >> 6;
        const int n = n0 + e;
        const bool valid = n < N_NODES;
        const float4* ap = (const float4*)(h + (size_t)n * HID) + qu * 8;
        #pragma unroll
        for (int i = 0; i < 8; ++i) {
            float4 v = valid ? ap[i] : make_float4(0.f, 0.f, 0.f, 0.f);
            int k = qu * 32 + i * 4;
            sA[(k + 0) * 64 + e] = v.x;
            sA[(k + 1) * 64 + e] = v.y;
            sA[(k + 2) * 64 + e] = v.z;
            sA[(k + 3) * 64 + e] = v.w;
        }
    }
    const int cg = tid & 15, eg = tid >> 4;
    const int c0 = cg * 8, ebase = eg * 4;

    for (int pass = 0; pass < 2; ++pass) {
        const float* wbase = w1 + (size_t)pass * HID * HID;
        float acc[4][8];
        #pragma unroll
        for (int i = 0; i < 4; ++i)
            #pragma unroll
            for (int j = 0; j < 8; ++j) acc[i][j] = 0.f;

        #pragma unroll
        for (int kt = 0; kt < HID; kt += 64) {
            __syncthreads();  // sW free (prev tile reads done); also makes sA visible
            {
                const int r = tid >> 2, qq = tid & 3;
                const float4* wp = (const float4*)(wbase + (size_t)(kt + r) * HID + qq * 32);
                float4* dp = (float4*)&sW[r * 132 + qq * 32];
                #pragma unroll
                for (int i = 0; i < 8; ++i) dp[i] = wp[i];
            }
            __syncthreads();
            #pragma unroll 16
            for (int kk = 0; kk < 64; ++kk) {
                const float4 av  = *(const float4*)&sA[(kt + kk) * 64 + ebase];
                const float4 w0  = *(const float4*)&sW[kk * 132 + c0];
                const float4 w1v = *(const float4*)&sW[kk * 132 + c0 + 4];
                const float a[4] = {av.x, av.y, av.z, av.w};
                const float w[8] = {w0.x, w0.y, w0.z, w0.w, w1v.x, w1v.y, w1v.z, w1v.w};
                #pragma unroll
                for (int i = 0; i < 4; ++i)
                    #pragma unroll
                    for (int j = 0; j < 8; ++j)
                        acc[i][j] = fmaf(a[i], w[j], acc[i][j]);
            }
        }
        float* outp = pass ? Q : P;
        #pragma unroll
        for (int i = 0; i < 4; ++i) {
            const int nn = n0 + ebase + i;
            if (nn < N_NODES) {
                *(float4*)&outp[(size_t)nn * HID + c0] =
                    make_float4(acc[i][0], acc[i][1], acc[i][2], acc[i][3]);
                *(float4*)&outp[(size_t)nn * HID + c0 + 4] =
                    make_float4(acc[i][4], acc[i][5], acc[i][6], acc[i][7]);
            }
        }
    }
}

// ------- per-edge: hidden = relu(P[src]+Q[dst]+attr*w1last+b1); agg[dst] += hidden@w2+b2 -------
__launch_bounds__(256, 2)
__global__ void k_edge(const float* __restrict__ P, const float* __restrict__ Q,
                       const int* __restrict__ esrc, const int* __restrict__ edst,
                       const float* __restrict__ attr,
                       const float* __restrict__ w1last, const float* __restrict__ b1,
                       const float* __restrict__ w2, const float* __restrict__ b2,
                       float* __restrict__ agg) {
    __shared__ float sT[64 * 132];   // hidden tile [e][k], padded
    __shared__ float sW[64 * 132];
    const int tid = threadIdx.x;
    const int e0 = blockIdx.x * 64;
    const int cg = tid & 15, eg = tid >> 4;
    const int c0 = cg * 8, ebase = eg * 4;

    float wl[8], bb[8];
    #pragma unroll
    for (int j = 0; j < 8; ++j) { wl[j] = w1last[c0 + j]; bb[j] = b1[c0 + j]; }

    int dstn[4];
    #pragma unroll
    for (int i = 0; i < 4; ++i) {
        const int e = e0 + ebase + i;
        const int s = esrc[e];
        const int d = edst[e];
        dstn[i] = d;
        const float a = attr[e];
        const float4 p0 = *(const float4*)&P[(size_t)s * HID + c0];
        const float4 p1 = *(const float4*)&P[(size_t)s * HID + c0 + 4];
        const float4 q0 = *(const float4*)&Q[(size_t)d * HID + c0];
        const float4 q1 = *(const float4*)&Q[(size_t)d * HID + c0 + 4];
        float hv[8] = {p0.x + q0.x, p0.y + q0.y, p0.z + q0.z, p0.w + q0.w,
                       p1.x + q1.x, p1.y + q1.y, p1.z + q1.z, p1.w + q1.w};
        #pragma unroll
        for (int j = 0; j < 8; ++j) hv[j] = fmaxf(fmaf(a, wl[j], hv[j] + bb[j]), 0.f);
        *(float4*)&sT[(ebase + i) * 132 + c0]     = make_float4(hv[0], hv[1], hv[2], hv[3]);
        *(float4*)&sT[(ebase + i) * 132 + c0 + 4] = make_float4(hv[4], hv[5], hv[6], hv[7]);
    }

    float acc[4][8];
    #pragma unroll
    for (int j = 0; j < 8; ++j) {
        const float bv = b2[c0 + j];
        #pragma unroll
        for (int i = 0; i < 4; ++i) acc[i][j] = bv;
    }

    #pragma unroll
    for (int kt = 0; kt < HID; kt += 64) {
        __syncthreads();  // sW free; first iter also publishes sT
        {
            const int r = tid >> 2, qq = tid & 3;
            const float4* wp = (const float4*)(w2 + (size_t)(kt + r) * HID + qq * 32);
            float4* dp = (float4*)&sW[r * 132 + qq * 32];
            #pragma unroll
            for (int i = 0; i < 8; ++i) dp[i] = wp[i];
        }
        __syncthreads();
        #pragma unroll 16
        for (int kk = 0; kk < 64; ++kk) {
            const float a0 = sT[(ebase + 0) * 132 + kt + kk];
            const float a1 = sT[(ebase + 1) * 132 + kt + kk];
            const float a2 = sT[(ebase + 2) * 132 + kt + kk];
            const float a3 = sT[(ebase + 3) * 132 + kt + kk];
            const float4 w0  = *(const float4*)&sW[kk * 132 + c0];
            const float4 w1v = *(const float4*)&sW[kk * 132 + c0 + 4];
            const float a[4] = {a0, a1, a2, a3};
            const float w[8] = {w0.x, w0.y, w0.z, w0.w, w1v.x, w1v.y, w1v.z, w1v.w};
            #pragma unroll
            for (int i = 0; i < 4; ++i)
                #pragma unroll
                for (int j = 0; j < 8; ++j)
                    acc[i][j] = fmaf(a[i], w[j], acc[i][j]);
        }
    }

    #pragma unroll
    for (int i = 0; i < 4; ++i) {
        float* ap = agg + (size_t)dstn[i] * HID + c0;
        #pragma unroll
        for (int j = 0; j < 8; ++j) atomicAdd(ap + j, acc[i][j]);
    }
}

// ------- h += relu([h|agg] @ uw1 + ub1) @ uw2 + ub2 -------
__launch_bounds__(256, 2)
__global__ void k_node_upd(float* __restrict__ h, const float* __restrict__ agg,
                           const float* __restrict__ uw1, const float* __restrict__ ub1,
                           const float* __restrict__ uw2, const float* __restrict__ ub2) {
    __shared__ float buf0[64 * 132];  // union: sA as [128][64] (8192 floats) then sT as [64][132]
    __shared__ float sW[64 * 132];
    const int tid = threadIdx.x;
    const int n0 = blockIdx.x * 64;
    const int e = tid & 63, qu = tid >> 6;
    const int cg = tid & 15, eg = tid >> 4;
    const int c0 = cg * 8, ebase = eg * 4;
    const int n_mine = n0 + e;
    const bool v_mine = n_mine < N_NODES;

    float acc[4][8];
    #pragma unroll
    for (int i = 0; i < 4; ++i)
        #pragma unroll
        for (int j = 0; j < 8; ++j) acc[i][j] = 0.f;

    for (int half = 0; half < 2; ++half) {
        const float* srcmat = half ? agg : h;
        __syncthreads();  // buf0 free (previous pass's reads done)
        {
            const float4* ap = (const float4*)(srcmat + (size_t)n_mine * HID) + qu * 8;
            #pragma unroll
            for (int i = 0; i < 8; ++i) {
                float4 v = v_mine ? ap[i] : make_float4(0.f, 0.f, 0.f, 0.f);
                int k = qu * 32 + i * 4;
                buf0[(k + 0) * 64 + e] = v.x;
                buf0[(k + 1) * 64 + e] = v.y;
                buf0[(k + 2) * 64 + e] = v.z;
                buf0[(k + 3) * 64 + e] = v.w;
            }
        }
        #pragma unroll
        for (int kt = 0; kt < HID; kt += 64) {
            __syncthreads();
            {
                const int r = tid >> 2, qq = tid & 3;
                const float4* wp =
                    (const float4*)(uw1 + (size_t)(half * HID + kt + r) * HID + qq * 32);
                float4* dp = (float4*)&sW[r * 132 + qq * 32];
                #pragma unroll
                for (int i = 0; i < 8; ++i) dp[i] = wp[i];
            }
            __syncthreads();
            #pragma unroll 16
            for (int kk = 0; kk < 64; ++kk) {
                const float4 av  = *(const float4*)&buf0[(kt + kk) * 64 + ebase];
                const float4 w0  = *(const float4*)&sW[kk * 132 + c0];
                const float4 w1v = *(const float4*)&sW[kk * 132 + c0 + 4];
                const float a[4] = {av.x, av.y, av.z, av.w};
                const float w[8] = {w0.x, w0.y, w0.z, w0.w, w1v.x, w1v.y, w1v.z, w1v.w};
                #pragma unroll
                for (int i = 0; i < 4; ++i)
                    #pragma unroll
                    for (int j = 0; j < 8; ++j)
                        acc[i][j] = fmaf(a[i], w[j], acc[i][j]);
            }
        }
    }

    __syncthreads();  // done reading buf0 as sA
    {
        float bv[8];
        #pragma unroll
        for (int j = 0; j < 8; ++j) bv[j] = ub1[c0 + j];
        #pragma unroll
        for (int i = 0; i < 4; ++i) {
            #pragma unroll
            for (int j = 0; j < 8; ++j) acc[i][j] = fmaxf(acc[i][j] + bv[j], 0.f);
            *(float4*)&buf0[(ebase + i) * 132 + c0] =
                make_float4(acc[i][0], acc[i][1], acc[i][2], acc[i][3]);
            *(float4*)&buf0[(ebase + i) * 132 + c0 + 4] =
                make_float4(acc[i][4], acc[i][5], acc[i][6], acc[i][7]);
        }
    }

    float acc2[4][8];
    #pragma unroll
    for (int j = 0; j < 8; ++j) {
        const float bv = ub2[c0 + j];
        #pragma unroll
        for (int i = 0; i < 4; ++i) acc2[i][j] = bv;
    }
    #pragma unroll
    for (int kt = 0; kt < HID; kt += 64) {
        __syncthreads();  // sW free; first iter publishes sT
        {
            const int r = tid >> 2, qq = tid & 3;
            const float4* wp = (const float4*)(uw2 + (size_t)(kt + r) * HID + qq * 32);
            float4* dp = (float4*)&sW[r * 132 + qq * 32];
            #pragma unroll
            for (int i = 0; i < 8; ++i) dp[i] = wp[i];
        }
        __syncthreads();
        #pragma unroll 16
        for (int kk = 0; kk < 64; ++kk) {
            const float a0 = buf0[(ebase + 0) * 132 + kt + kk];
            const float a1 = buf0[(ebase + 1) * 132 + kt + kk];
            const float a2 = buf0[(ebase + 2) * 132 + kt + kk];
            const float a3 = buf0[(ebase + 3) * 132 + kt + kk];
            const float4 w0  = *(const float4*)&sW[kk * 132 + c0];
            const float4 w1v = *(const float4*)&sW[kk * 132 + c0 + 4];
            const float a[4] = {a0, a1, a2, a3};
            const float w[8] = {w0.x, w0.y, w0.z, w0.w, w1v.x, w1v.y, w1v.z, w1v.w};
            #pragma unroll
            for (int i = 0; i < 4; ++i)
                #pragma unroll
                for (int j = 0; j < 8; ++j)
                    acc2[i][j] = fmaf(a[i], w[j], acc2[i][j]);
        }
    }
    #pragma unroll
    for (int i = 0; i < 4; ++i) {
        const int nn = n0 + ebase + i;
        if (nn < N_NODES) {
            float4 h0 = *(float4*)&h[(size_t)nn * HID + c0];
            float4 h1 = *(float4*)&h[(size_t)nn * HID + c0 + 4];
            h0.x += acc2[i][0]; h0.y += acc2[i][1]; h0.z += acc2[i][2]; h0.w += acc2[i][3];
            h1.x += acc2[i][4]; h1.y += acc2[i][5]; h1.z += acc2[i][6]; h1.w += acc2[i][7];
            *(float4*)&h[(size_t)nn * HID + c0] = h0;
            *(float4*)&h[(size_t)nn * HID + c0 + 4] = h1;
        }
    }
}

// ---------------- pooling (batch is sorted) ----------------
__device__ inline int lb(const int* a, int n, int v) {
    int lo = 0, hi = n;
    while (lo < hi) { int m = (lo + hi) >> 1; if (a[m] < v) lo = m + 1; else hi = m; }
    return lo;
}

__global__ void k_pool(const float* __restrict__ h, const int* __restrict__ batch,
                       float* __restrict__ pooled, float* __restrict__ counts) {
    const int g = blockIdx.x >> 2, part = blockIdx.x & 3;
    __shared__ int sb[2];
    if (threadIdx.x == 0) { sb[0] = lb(batch, N_NODES, g); sb[1] = lb(batch, N_NODES, g + 1); }
    __syncthreads();
    const int lo = sb[0], hi = sb[1], cnt = hi - lo;
    if (threadIdx.x == 0 && part == 0) counts[g] = (float)cnt;
    const int per = (cnt + 3) >> 2;
    const int a = lo + part * per;
    const int b = min(a + per, hi);
    const int c = threadIdx.x;  // 128 threads = channels
    float s = 0.f;
    for (int n = a; n < b; ++n) s += h[(size_t)n * HID + c];
    if (b > a) atomicAdd(&pooled[g * HID + c], s);
}

// ---------------- head MLP ----------------
__global__ void k_head(const float* __restrict__ pooled, const float* __restrict__ counts,
                       const float* __restrict__ hw1, const float* __restrict__ hb1,
                       const float* __restrict__ hw2, const float* __restrict__ hb2,
                       float* __restrict__ out) {
    const int g = blockIdx.x;
    const int c = threadIdx.x;  // 128
    __shared__ float sp[HID];
    __shared__ float red[HID];
    const float cnt = fmaxf(counts[g], 1.f);
    sp[c] = pooled[g * HID + c] / cnt;
    __syncthreads();
    float acc = hb1[c];
    #pragma unroll 8
    for (int k = 0; k < HID; ++k) acc = fmaf(sp[k], hw1[k * HID + c], acc);
    red[c] = fmaxf(acc, 0.f) * hw2[c];
    __syncthreads();
    for (int s = 64; s > 0; s >>= 1) {
        if (c < s) red[c] += red[c + s];
        __syncthreads();
    }
    if (c == 0) out[g] = red[0] + hb2[0];
}

extern "C" void kernel_launch(void* const* d_in, const int* in_sizes, int n_in,
                              void* d_out, int out_size, void* d_ws, size_t ws_size,
                              hipStream_t stream) {
    const int*   z       = (const int*)d_in[0];
    const int*   ei      = (const int*)d_in[1];
    const float* eattr   = (const float*)d_in[2];
    const int*   batch   = (const int*)d_in[3];
    const float* embed   = (const float*)d_in[4];
    const float* msg_w1  = (const float*)d_in[5];
    const float* msg_b1  = (const float*)d_in[6];
    const float* msg_w2  = (const float*)d_in[7];
    const float* msg_b2  = (const float*)d_in[8];
    const float* upd_w1  = (const float*)d_in[9];
    const float* upd_b1  = (const float*)d_in[10];
    const float* upd_w2  = (const float*)d_in[11];
    const float* upd_b2  = (const float*)d_in[12];
    const float* head_w1 = (const float*)d_in[13];
    const float* head_b1 = (const float*)d_in[14];
    const float* head_w2 = (const float*)d_in[15];
    const float* head_b2 = (const float*)d_in[16];
    float* out = (float*)d_out;

    // workspace layout (~102.5 MB)
    float* h      = (float*)d_ws;
    float* P      = h + (size_t)N_NODES * HID;
    float* Q      = P + (size_t)N_NODES * HID;
    float* agg    = Q + (size_t)N_NODES * HID;
    float* pooled = agg + (size_t)N_NODES * HID;
    float* counts = pooled + NUM_GRAPHS * HID;

    const int* esrc = ei;
    const int* edst = ei + N_EDGES;

    k_embed<<<(N_NODES * 32 + 255) / 256, 256, 0, stream>>>(z, (const float4*)embed, (float4*)h);

    for (int l = 0; l < 3; ++l) {
        const float* w1 = msg_w1 + (size_t)l * 257 * HID;
        k_node_pre<<<(N_NODES + 63) / 64, 256, 0, stream>>>(h, w1, P, Q);
        hipMemsetAsync(agg, 0, (size_t)N_NODES * HID * sizeof(float), stream);
        k_edge<<<N_EDGES / 64, 256, 0, stream>>>(P, Q, esrc, edst, eattr,
            w1 + 256 * HID, msg_b1 + (size_t)l * HID,
            msg_w2 + (size_t)l * HID * HID, msg_b2 + (size_t)l * HID, agg);
        k_node_upd<<<(N_NODES + 63) / 64, 256, 0, stream>>>(h, agg,
            upd_w1 + (size_t)l * 256 * HID, upd_b1 + (size_t)l * HID,
            upd_w2 + (size_t)l * HID * HID, upd_b2 + (size_t)l * HID);
    }
    hipMemsetAsync(pooled, 0, (NUM_GRAPHS * HID + NUM_GRAPHS) * sizeof(float), stream);
    k_pool<<<NUM_GRAPHS * 4, 128, 0, stream>>>(h, batch, pooled, counts);
    k_head<<<NUM_GRAPHS, 128, 0, stream>>>(pooled, counts, head_w1, head_b1, head_w2, head_b2, out);
}

// Round 2
// 807.752 us; speedup vs baseline: 6.1796x; 6.1796x over previous
//
#include <hip/hip_runtime.h>

#define N_NODES 50000
#define N_EDGES 400000
#define HID 128
#define NUM_GRAPHS 64
#define SCAN_B 196  // ceil(N_NODES/256)

// ---------------- embed gather: h = embed[z] ----------------
__global__ void k_embed(const int* __restrict__ z, const float4* __restrict__ embed4,
                        float4* __restrict__ h4) {
    int idx = blockIdx.x * 256 + threadIdx.x;
    if (idx >= N_NODES * 32) return;
    int node = idx >> 5;
    int c = idx & 31;
    h4[idx] = embed4[(size_t)z[node] * 32 + c];
}

// ---------------- CSR build: histogram, scan, scatter ----------------
__global__ void k_hist(const int* __restrict__ edst, int* __restrict__ deg) {
    int e = blockIdx.x * 256 + threadIdx.x;
    if (e < N_EDGES) atomicAdd(&deg[edst[e]], 1);
}

__global__ void k_scan1(const int* __restrict__ deg, int* __restrict__ partial) {
    __shared__ int buf[256];
    int i = blockIdx.x * 256 + threadIdx.x;
    buf[threadIdx.x] = (i < N_NODES) ? deg[i] : 0;
    __syncthreads();
    for (int off = 128; off > 0; off >>= 1) {
        if (threadIdx.x < off) buf[threadIdx.x] += buf[threadIdx.x + off];
        __syncthreads();
    }
    if (threadIdx.x == 0) partial[blockIdx.x] = buf[0];
}

__global__ void k_scan2(int* __restrict__ partial, int* __restrict__ row_ptr) {
    __shared__ int buf[256];
    int v = (threadIdx.x < SCAN_B) ? partial[threadIdx.x] : 0;
    buf[threadIdx.x] = v;
    __syncthreads();
    for (int off = 1; off < 256; off <<= 1) {
        int t = (threadIdx.x >= off) ? buf[threadIdx.x - off] : 0;
        __syncthreads();
        buf[threadIdx.x] += t;
        __syncthreads();
    }
    if (threadIdx.x < SCAN_B) partial[threadIdx.x] = buf[threadIdx.x] - v;  // exclusive
    if (threadIdx.x == 255) row_ptr[N_NODES] = buf[255];
}

__global__ void k_scan3(const int* __restrict__ deg, const int* __restrict__ partial,
                        int* __restrict__ row_ptr, int* __restrict__ cursor) {
    __shared__ int buf[256];
    int i = blockIdx.x * 256 + threadIdx.x;
    int v = (i < N_NODES) ? deg[i] : 0;
    buf[threadIdx.x] = v;
    __syncthreads();
    for (int off = 1; off < 256; off <<= 1) {
        int t = (threadIdx.x >= off) ? buf[threadIdx.x - off] : 0;
        __syncthreads();
        buf[threadIdx.x] += t;
        __syncthreads();
    }
    if (i < N_NODES) {
        int ex = partial[blockIdx.x] + buf[threadIdx.x] - v;
        row_ptr[i] = ex;
        cursor[i] = ex;
    }
}

__global__ void k_scatter(const int* __restrict__ esrc, const int* __restrict__ edst,
                          const float* __restrict__ attr, int* __restrict__ cursor,
                          int* __restrict__ s_src, float* __restrict__ s_attr) {
    int e = blockIdx.x * 256 + threadIdx.x;
    if (e >= N_EDGES) return;
    int p = atomicAdd(&cursor[edst[e]], 1);
    s_src[p] = esrc[e];
    s_attr[p] = attr[e];
}

// ---------------- P = h @ w1a, Q = h @ w1b + b1 ----------------
__launch_bounds__(256, 2)
__global__ void k_node_pre(const float* __restrict__ h, const float* __restrict__ w1,
                           const float* __restrict__ b1,
                           float* __restrict__ P, float* __restrict__ Q) {
    __shared__ float sA[HID * 64];   // [k][e] transposed
    __shared__ float sW[64 * 132];   // k-tile of W, padded
    const int tid = threadIdx.x;
    const int n0 = blockIdx.x * 64;
    {
        const int e = tid & 63, qu = tid >> 6;
        const int n = n0 + e;
        const bool valid = n < N_NODES;
        const float4* ap = (const float4*)(h + (size_t)n * HID) + qu * 8;
        #pragma unroll
        for (int i = 0; i < 8; ++i) {
            float4 v = valid ? ap[i] : make_float4(0.f, 0.f, 0.f, 0.f);
            int k = qu * 32 + i * 4;
            sA[(k + 0) * 64 + e] = v.x;
            sA[(k + 1) * 64 + e] = v.y;
            sA[(k + 2) * 64 + e] = v.z;
            sA[(k + 3) * 64 + e] = v.w;
        }
    }
    const int cg = tid & 15, eg = tid >> 4;
    const int c0 = cg * 8, ebase = eg * 4;

    for (int pass = 0; pass < 2; ++pass) {
        const float* wbase = w1 + (size_t)pass * HID * HID;
        float acc[4][8];
        #pragma unroll
        for (int i = 0; i < 4; ++i)
            #pragma unroll
            for (int j = 0; j < 8; ++j) acc[i][j] = 0.f;

        #pragma unroll
        for (int kt = 0; kt < HID; kt += 64) {
            __syncthreads();
            {
                const int r = tid >> 2, qq = tid & 3;
                const float4* wp = (const float4*)(wbase + (size_t)(kt + r) * HID + qq * 32);
                float4* dp = (float4*)&sW[r * 132 + qq * 32];
                #pragma unroll
                for (int i = 0; i < 8; ++i) dp[i] = wp[i];
            }
            __syncthreads();
            #pragma unroll 16
            for (int kk = 0; kk < 64; ++kk) {
                const float4 av  = *(const float4*)&sA[(kt + kk) * 64 + ebase];
                const float4 w0  = *(const float4*)&sW[kk * 132 + c0];
                const float4 w1v = *(const float4*)&sW[kk * 132 + c0 + 4];
                const float a[4] = {av.x, av.y, av.z, av.w};
                const float w[8] = {w0.x, w0.y, w0.z, w0.w, w1v.x, w1v.y, w1v.z, w1v.w};
                #pragma unroll
                for (int i = 0; i < 4; ++i)
                    #pragma unroll
                    for (int j = 0; j < 8; ++j)
                        acc[i][j] = fmaf(a[i], w[j], acc[i][j]);
            }
        }
        float* outp = pass ? Q : P;
        #pragma unroll
        for (int i = 0; i < 4; ++i) {
            const int nn = n0 + ebase + i;
            if (nn < N_NODES) {
                float b0 = 0.f, b1v = 0.f, b2v = 0.f, b3 = 0.f, b4 = 0.f, b5 = 0.f, b6 = 0.f, b7 = 0.f;
                if (pass) {
                    b0 = b1[c0 + 0]; b1v = b1[c0 + 1]; b2v = b1[c0 + 2]; b3 = b1[c0 + 3];
                    b4 = b1[c0 + 4]; b5 = b1[c0 + 5]; b6 = b1[c0 + 6]; b7 = b1[c0 + 7];
                }
                *(float4*)&outp[(size_t)nn * HID + c0] =
                    make_float4(acc[i][0] + b0, acc[i][1] + b1v, acc[i][2] + b2v, acc[i][3] + b3);
                *(float4*)&outp[(size_t)nn * HID + c0 + 4] =
                    make_float4(acc[i][4] + b4, acc[i][5] + b5, acc[i][6] + b6, acc[i][7] + b7);
            }
        }
    }
}

// ---------------- W2U = w2 @ uw1_bot, b2u = b2 @ uw1_bot ----------------
__global__ void k_small(const float* __restrict__ w2, const float* __restrict__ uw1,
                        const float* __restrict__ b2,
                        float* __restrict__ W2U, float* __restrict__ b2u) {
    __shared__ float row[HID];
    const int k = blockIdx.x, j = threadIdx.x;
    const float* src = (k < HID) ? &w2[(size_t)k * HID] : b2;
    row[j] = src[j];
    __syncthreads();
    float acc = 0.f;
    #pragma unroll 8
    for (int m = 0; m < HID; ++m)
        acc = fmaf(row[m], uw1[(size_t)(HID + m) * HID + j], acc);
    if (k < HID) W2U[(size_t)k * HID + j] = acc;
    else b2u[j] = acc;
}

// ---------------- aggH[n] = sum_e relu(P[src_e] + Q[n] + attr_e * w1last) ----------------
__global__ void k_agg(const float* __restrict__ P, const float* __restrict__ Q,
                      const int* __restrict__ row_ptr, const int* __restrict__ s_src,
                      const float* __restrict__ s_attr, const float* __restrict__ w1last,
                      float* __restrict__ aggH) {
    const int n = blockIdx.x * 8 + (threadIdx.x >> 5);
    const int c0 = (threadIdx.x & 31) * 4;
    if (n >= N_NODES) return;
    const float4 q  = *(const float4*)&Q[(size_t)n * HID + c0];
    const float4 wl = *(const float4*)&w1last[c0];
    float4 acc = make_float4(0.f, 0.f, 0.f, 0.f);
    const int lo = row_ptr[n], hi = row_ptr[n + 1];
    for (int e = lo; e < hi; ++e) {
        const int s = s_src[e];
        const float a = s_attr[e];
        const float4 p = *(const float4*)&P[(size_t)s * HID + c0];
        acc.x += fmaxf(fmaf(a, wl.x, p.x + q.x), 0.f);
        acc.y += fmaxf(fmaf(a, wl.y, p.y + q.y), 0.f);
        acc.z += fmaxf(fmaf(a, wl.z, p.z + q.z), 0.f);
        acc.w += fmaxf(fmaf(a, wl.w, p.w + q.w), 0.f);
    }
    *(float4*)&aggH[(size_t)n * HID + c0] = acc;
}

// ------- h += relu(h@uw1_top + aggH@W2U + ub1 + deg*b2u) @ uw2 + ub2 -------
__launch_bounds__(256, 2)
__global__ void k_node_upd(float* __restrict__ h, const float* __restrict__ aggH,
                           const float* __restrict__ uw1, const float* __restrict__ W2U,
                           const float* __restrict__ ub1, const float* __restrict__ b2u,
                           const int* __restrict__ row_ptr,
                           const float* __restrict__ uw2, const float* __restrict__ ub2) {
    __shared__ float buf0[64 * 132];  // union: sA [128][64] then sT [64][132]
    __shared__ float sW[64 * 132];
    const int tid = threadIdx.x;
    const int n0 = blockIdx.x * 64;
    const int e = tid & 63, qu = tid >> 6;
    const int cg = tid & 15, eg = tid >> 4;
    const int c0 = cg * 8, ebase = eg * 4;
    const int n_mine = n0 + e;
    const bool v_mine = n_mine < N_NODES;

    float acc[4][8];
    #pragma unroll
    for (int i = 0; i < 4; ++i)
        #pragma unroll
        for (int j = 0; j < 8; ++j) acc[i][j] = 0.f;

    for (int half = 0; half < 2; ++half) {
        const float* srcmat = half ? aggH : h;
        const float* wmat = half ? W2U : uw1;
        __syncthreads();
        {
            const float4* ap = (const float4*)(srcmat + (size_t)n_mine * HID) + qu * 8;
            #pragma unroll
            for (int i = 0; i < 8; ++i) {
                float4 v = v_mine ? ap[i] : make_float4(0.f, 0.f, 0.f, 0.f);
                int k = qu * 32 + i * 4;
                buf0[(k + 0) * 64 + e] = v.x;
                buf0[(k + 1) * 64 + e] = v.y;
                buf0[(k + 2) * 64 + e] = v.z;
                buf0[(k + 3) * 64 + e] = v.w;
            }
        }
        #pragma unroll
        for (int kt = 0; kt < HID; kt += 64) {
            __syncthreads();
            {
                const int r = tid >> 2, qq = tid & 3;
                const float4* wp = (const float4*)(wmat + (size_t)(kt + r) * HID + qq * 32);
                float4* dp = (float4*)&sW[r * 132 + qq * 32];
                #pragma unroll
                for (int i = 0; i < 8; ++i) dp[i] = wp[i];
            }
            __syncthreads();
            #pragma unroll 16
            for (int kk = 0; kk < 64; ++kk) {
                const float4 av  = *(const float4*)&buf0[(kt + kk) * 64 + ebase];
                const float4 w0  = *(const float4*)&sW[kk * 132 + c0];
                const float4 w1v = *(const float4*)&sW[kk * 132 + c0 + 4];
                const float a[4] = {av.x, av.y, av.z, av.w};
                const float w[8] = {w0.x, w0.y, w0.z, w0.w, w1v.x, w1v.y, w1v.z, w1v.w};
                #pragma unroll
                for (int i = 0; i < 4; ++i)
                    #pragma unroll
                    for (int j = 0; j < 8; ++j)
                        acc[i][j] = fmaf(a[i], w[j], acc[i][j]);
            }
        }
    }

    __syncthreads();  // done reading buf0 as sA
    {
        float bv[8], b2v[8];
        #pragma unroll
        for (int j = 0; j < 8; ++j) { bv[j] = ub1[c0 + j]; b2v[j] = b2u[c0 + j]; }
        #pragma unroll
        for (int i = 0; i < 4; ++i) {
            const int nn = n0 + ebase + i;
            float deg = 0.f;
            if (nn < N_NODES) deg = (float)(row_ptr[nn + 1] - row_ptr[nn]);
            #pragma unroll
            for (int j = 0; j < 8; ++j)
                acc[i][j] = fmaxf(acc[i][j] + bv[j] + deg * b2v[j], 0.f);
            *(float4*)&buf0[(ebase + i) * 132 + c0] =
                make_float4(acc[i][0], acc[i][1], acc[i][2], acc[i][3]);
            *(float4*)&buf0[(ebase + i) * 132 + c0 + 4] =
                make_float4(acc[i][4], acc[i][5], acc[i][6], acc[i][7]);
        }
    }

    float acc2[4][8];
    #pragma unroll
    for (int j = 0; j < 8; ++j) {
        const float bv = ub2[c0 + j];
        #pragma unroll
        for (int i = 0; i < 4; ++i) acc2[i][j] = bv;
    }
    #pragma unroll
    for (int kt = 0; kt < HID; kt += 64) {
        __syncthreads();
        {
            const int r = tid >> 2, qq = tid & 3;
            const float4* wp = (const float4*)(uw2 + (size_t)(kt + r) * HID + qq * 32);
            float4* dp = (float4*)&sW[r * 132 + qq * 32];
            #pragma unroll
            for (int i = 0; i < 8; ++i) dp[i] = wp[i];
        }
        __syncthreads();
        #pragma unroll 16
        for (int kk = 0; kk < 64; ++kk) {
            const float a0 = buf0[(ebase + 0) * 132 + kt + kk];
            const float a1 = buf0[(ebase + 1) * 132 + kt + kk];
            const float a2 = buf0[(ebase + 2) * 132 + kt + kk];
            const float a3 = buf0[(ebase + 3) * 132 + kt + kk];
            const float4 w0  = *(const float4*)&sW[kk * 132 + c0];
            const float4 w1v = *(const float4*)&sW[kk * 132 + c0 + 4];
            const float a[4] = {a0, a1, a2, a3};
            const float w[8] = {w0.x, w0.y, w0.z, w0.w, w1v.x, w1v.y, w1v.z, w1v.w};
            #pragma unroll
            for (int i = 0; i < 4; ++i)
                #pragma unroll
                for (int j = 0; j < 8; ++j)
                    acc2[i][j] = fmaf(a[i], w[j], acc2[i][j]);
        }
    }
    #pragma unroll
    for (int i = 0; i < 4; ++i) {
        const int nn = n0 + ebase + i;
        if (nn < N_NODES) {
            float4 h0 = *(float4*)&h[(size_t)nn * HID + c0];
            float4 h1 = *(float4*)&h[(size_t)nn * HID + c0 + 4];
            h0.x += acc2[i][0]; h0.y += acc2[i][1]; h0.z += acc2[i][2]; h0.w += acc2[i][3];
            h1.x += acc2[i][4]; h1.y += acc2[i][5]; h1.z += acc2[i][6]; h1.w += acc2[i][7];
            *(float4*)&h[(size_t)nn * HID + c0] = h0;
            *(float4*)&h[(size_t)nn * HID + c0 + 4] = h1;
        }
    }
}

// ---------------- pooling (batch is sorted) ----------------
__device__ inline int lb(const int* a, int n, int v) {
    int lo = 0, hi = n;
    while (lo < hi) { int m = (lo + hi) >> 1; if (a[m] < v) lo = m + 1; else hi = m; }
    return lo;
}

__global__ void k_pool(const float* __restrict__ h, const int* __restrict__ batch,
                       float* __restrict__ pooled, float* __restrict__ counts) {
    const int g = blockIdx.x >> 2, part = blockIdx.x & 3;
    __shared__ int sb[2];
    if (threadIdx.x == 0) { sb[0] = lb(batch, N_NODES, g); sb[1] = lb(batch, N_NODES, g + 1); }
    __syncthreads();
    const int lo = sb[0], hi = sb[1], cnt = hi - lo;
    if (threadIdx.x == 0 && part == 0) counts[g] = (float)cnt;
    const int per = (cnt + 3) >> 2;
    const int a = lo + part * per;
    const int b = min(a + per, hi);
    const int c = threadIdx.x;
    float s = 0.f;
    for (int n = a; n < b; ++n) s += h[(size_t)n * HID + c];
    if (b > a) atomicAdd(&pooled[g * HID + c], s);
}

// ---------------- head MLP ----------------
__global__ void k_head(const float* __restrict__ pooled, const float* __restrict__ counts,
                       const float* __restrict__ hw1, const float* __restrict__ hb1,
                       const float* __restrict__ hw2, const float* __restrict__ hb2,
                       float* __restrict__ out) {
    const int g = blockIdx.x;
    const int c = threadIdx.x;
    __shared__ float sp[HID];
    __shared__ float red[HID];
    const float cnt = fmaxf(counts[g], 1.f);
    sp[c] = pooled[g * HID + c] / cnt;
    __syncthreads();
    float acc = hb1[c];
    #pragma unroll 8
    for (int k = 0; k < HID; ++k) acc = fmaf(sp[k], hw1[k * HID + c], acc);
    red[c] = fmaxf(acc, 0.f) * hw2[c];
    __syncthreads();
    for (int s = 64; s > 0; s >>= 1) {
        if (c < s) red[c] += red[c + s];
        __syncthreads();
    }
    if (c == 0) out[g] = red[0] + hb2[0];
}

extern "C" void kernel_launch(void* const* d_in, const int* in_sizes, int n_in,
                              void* d_out, int out_size, void* d_ws, size_t ws_size,
                              hipStream_t stream) {
    const int*   z       = (const int*)d_in[0];
    const int*   ei      = (const int*)d_in[1];
    const float* eattr   = (const float*)d_in[2];
    const int*   batch   = (const int*)d_in[3];
    const float* embed   = (const float*)d_in[4];
    const float* msg_w1  = (const float*)d_in[5];
    const float* msg_b1  = (const float*)d_in[6];
    const float* msg_w2  = (const float*)d_in[7];
    const float* msg_b2  = (const float*)d_in[8];
    const float* upd_w1  = (const float*)d_in[9];
    const float* upd_b1  = (const float*)d_in[10];
    const float* upd_w2  = (const float*)d_in[11];
    const float* upd_b2  = (const float*)d_in[12];
    const float* head_w1 = (const float*)d_in[13];
    const float* head_b1 = (const float*)d_in[14];
    const float* head_w2 = (const float*)d_in[15];
    const float* head_b2 = (const float*)d_in[16];
    float* out = (float*)d_out;

    // workspace layout (~106.3 MB)
    float* h      = (float*)d_ws;
    float* P      = h + (size_t)N_NODES * HID;
    float* Q      = P + (size_t)N_NODES * HID;
    float* aggH   = Q + (size_t)N_NODES * HID;
    float* W2U    = aggH + (size_t)N_NODES * HID;
    float* b2u    = W2U + HID * HID;
    float* pooled = b2u + HID;
    float* counts = pooled + NUM_GRAPHS * HID;
    float* s_attr = counts + NUM_GRAPHS;
    int* deg_i    = (int*)(s_attr + N_EDGES);
    int* row_ptr  = deg_i + N_NODES;
    int* partial  = row_ptr + N_NODES + 1;
    int* cursor   = partial + 256;
    int* s_src    = cursor + N_NODES;

    const int* esrc = ei;
    const int* edst = ei + N_EDGES;

    k_embed<<<(N_NODES * 32 + 255) / 256, 256, 0, stream>>>(z, (const float4*)embed, (float4*)h);

    // CSR build (per call; edges are static but no caching allowed)
    hipMemsetAsync(deg_i, 0, N_NODES * sizeof(int), stream);
    k_hist<<<(N_EDGES + 255) / 256, 256, 0, stream>>>(edst, deg_i);
    k_scan1<<<SCAN_B, 256, 0, stream>>>(deg_i, partial);
    k_scan2<<<1, 256, 0, stream>>>(partial, row_ptr);
    k_scan3<<<SCAN_B, 256, 0, stream>>>(deg_i, partial, row_ptr, cursor);
    k_scatter<<<(N_EDGES + 255) / 256, 256, 0, stream>>>(esrc, edst, eattr, cursor, s_src, s_attr);

    for (int l = 0; l < 3; ++l) {
        const float* w1 = msg_w1 + (size_t)l * 257 * HID;
        k_node_pre<<<(N_NODES + 63) / 64, 256, 0, stream>>>(
            h, w1, msg_b1 + (size_t)l * HID, P, Q);
        k_small<<<HID + 1, HID, 0, stream>>>(
            msg_w2 + (size_t)l * HID * HID, upd_w1 + (size_t)l * 2 * HID * HID,
            msg_b2 + (size_t)l * HID, W2U, b2u);
        k_agg<<<(N_NODES + 7) / 8, 256, 0, stream>>>(
            P, Q, row_ptr, s_src, s_attr, w1 + 256 * HID, aggH);
        k_node_upd<<<(N_NODES + 63) / 64, 256, 0, stream>>>(
            h, aggH, upd_w1 + (size_t)l * 2 * HID * HID, W2U,
            upd_b1 + (size_t)l * HID, b2u, row_ptr,
            upd_w2 + (size_t)l * HID * HID, upd_b2 + (size_t)l * HID);
    }
    hipMemsetAsync(pooled, 0, (NUM_GRAPHS * HID + NUM_GRAPHS) * sizeof(float), stream);
    k_pool<<<NUM_GRAPHS * 4, 128, 0, stream>>>(h, batch, pooled, counts);
    k_head<<<NUM_GRAPHS, 128, 0, stream>>>(pooled, counts, head_w1, head_b1, head_w2, head_b2, out);
}

// Round 3
// 564.723 us; speedup vs baseline: 8.8390x; 1.4304x over previous
//
#include <hip/hip_runtime.h>

#define N_NODES 50000
#define N_EDGES 400000
#define HID 128
#define NUM_GRAPHS 64
#define SCAN_B 196  // ceil(N_NODES/256)

typedef __bf16 bf16;
typedef bf16 bf16x8 __attribute__((ext_vector_type(8)));
typedef float f32x4 __attribute__((ext_vector_type(4)));

// ---------------- embed gather: h = embed[z] ----------------
__global__ void k_embed(const int* __restrict__ z, const float4* __restrict__ embed4,
                        float4* __restrict__ h4) {
    int idx = blockIdx.x * 256 + threadIdx.x;
    if (idx >= N_NODES * 32) return;
    int node = idx >> 5;
    int c = idx & 31;
    h4[idx] = embed4[(size_t)z[node] * 32 + c];
}

// ---------------- CSR build: histogram, scan, scatter ----------------
__global__ void k_hist(const int* __restrict__ edst, int* __restrict__ deg) {
    int e = blockIdx.x * 256 + threadIdx.x;
    if (e < N_EDGES) atomicAdd(&deg[edst[e]], 1);
}

__global__ void k_scan1(const int* __restrict__ deg, int* __restrict__ partial) {
    __shared__ int buf[256];
    int i = blockIdx.x * 256 + threadIdx.x;
    buf[threadIdx.x] = (i < N_NODES) ? deg[i] : 0;
    __syncthreads();
    for (int off = 128; off > 0; off >>= 1) {
        if (threadIdx.x < off) buf[threadIdx.x] += buf[threadIdx.x + off];
        __syncthreads();
    }
    if (threadIdx.x == 0) partial[blockIdx.x] = buf[0];
}

__global__ void k_scan2(int* __restrict__ partial, int* __restrict__ row_ptr) {
    __shared__ int buf[256];
    int v = (threadIdx.x < SCAN_B) ? partial[threadIdx.x] : 0;
    buf[threadIdx.x] = v;
    __syncthreads();
    for (int off = 1; off < 256; off <<= 1) {
        int t = (threadIdx.x >= off) ? buf[threadIdx.x - off] : 0;
        __syncthreads();
        buf[threadIdx.x] += t;
        __syncthreads();
    }
    if (threadIdx.x < SCAN_B) partial[threadIdx.x] = buf[threadIdx.x] - v;  // exclusive
    if (threadIdx.x == 255) row_ptr[N_NODES] = buf[255];
}

__global__ void k_scan3(const int* __restrict__ deg, const int* __restrict__ partial,
                        int* __restrict__ row_ptr, int* __restrict__ cursor,
                        float* __restrict__ degf) {
    __shared__ int buf[256];
    int i = blockIdx.x * 256 + threadIdx.x;
    int v = (i < N_NODES) ? deg[i] : 0;
    buf[threadIdx.x] = v;
    __syncthreads();
    for (int off = 1; off < 256; off <<= 1) {
        int t = (threadIdx.x >= off) ? buf[threadIdx.x - off] : 0;
        __syncthreads();
        buf[threadIdx.x] += t;
        __syncthreads();
    }
    if (i < N_NODES) {
        int ex = partial[blockIdx.x] + buf[threadIdx.x] - v;
        row_ptr[i] = ex;
        cursor[i] = ex;
        degf[i] = (float)v;
    }
}

__global__ void k_scatter(const int* __restrict__ esrc, const int* __restrict__ edst,
                          const float* __restrict__ attr, int* __restrict__ cursor,
                          int* __restrict__ s_src, float* __restrict__ s_attr) {
    int e = blockIdx.x * 256 + threadIdx.x;
    if (e >= N_EDGES) return;
    int p = atomicAdd(&cursor[edst[e]], 1);
    s_src[p] = esrc[e];
    s_attr[p] = attr[e];
}

// ---------------- weight prep: transpose+convert to bf16 [n][k] ----------------
// n<256: W1t from w1 (rows 0..255); 256<=n<384: U1t from uw1 top; else: U2t from uw2.
__global__ void k_wprep(const float* __restrict__ w1, const float* __restrict__ uw1,
                        const float* __restrict__ uw2,
                        bf16* __restrict__ W1t, bf16* __restrict__ U1t,
                        bf16* __restrict__ U2t) {
    const int n = blockIdx.x, k = threadIdx.x;
    if (n < 256) {
        W1t[n * HID + k] = (bf16)w1[(size_t)((n & 128) + k) * HID + (n & 127)];
    } else if (n < 384) {
        const int nn = n - 256;
        U1t[nn * HID + k] = (bf16)uw1[(size_t)k * HID + nn];
    } else {
        const int nn = n - 384;
        U2t[nn * HID + k] = (bf16)uw2[(size_t)k * HID + nn];
    }
}

// ---------------- W2Ut[j][k] = (w2 @ uw1_bot)[k][j] (bf16); b2u = b2 @ uw1_bot ----------------
__global__ void k_small(const float* __restrict__ w2, const float* __restrict__ uw1,
                        const float* __restrict__ b2,
                        bf16* __restrict__ W2Ut, float* __restrict__ b2u) {
    __shared__ float row[HID];
    const int k = blockIdx.x, j = threadIdx.x;
    const float* src = (k < HID) ? &w2[(size_t)k * HID] : b2;
    row[j] = src[j];
    __syncthreads();
    float acc = 0.f;
    #pragma unroll 8
    for (int m = 0; m < HID; ++m)
        acc = fmaf(row[m], uw1[(size_t)(HID + m) * HID + j], acc);
    if (k < HID) W2Ut[(size_t)j * HID + k] = (bf16)acc;
    else b2u[j] = acc;
}

// ---------------- [P|Q] = hb @ W1t^T (MFMA); Q gets +b1 ----------------
__launch_bounds__(256, 3)
__global__ void k_node_pre(const float* __restrict__ h, const bf16* __restrict__ W1t,
                           const float* __restrict__ b1,
                           float* __restrict__ P, float* __restrict__ Q) {
    __shared__ bf16 sA[64 * 136];  // [row][k], +8 pad
    const int tid = threadIdx.x;
    const int n0 = blockIdx.x * 64;
    {
        const int r = tid & 63, cg = tid >> 6;
        const bool valid = (n0 + r) < N_NODES;
        const float4* src = (const float4*)(h + (size_t)(n0 + r) * HID + cg * 32);
        #pragma unroll
        for (int i = 0; i < 4; ++i) {
            float4 a = valid ? src[2 * i] : make_float4(0.f, 0.f, 0.f, 0.f);
            float4 b = valid ? src[2 * i + 1] : make_float4(0.f, 0.f, 0.f, 0.f);
            bf16x8 v;
            v[0] = (bf16)a.x; v[1] = (bf16)a.y; v[2] = (bf16)a.z; v[3] = (bf16)a.w;
            v[4] = (bf16)b.x; v[5] = (bf16)b.y; v[6] = (bf16)b.z; v[7] = (bf16)b.w;
            *(bf16x8*)&sA[r * 136 + cg * 32 + i * 8] = v;
        }
    }
    __syncthreads();
    const int lane = tid & 63, wave = tid >> 6;
    const int lr = lane & 15, kq = (lane >> 4) * 8;
    const int bcol = wave * 64;

    const f32x4 z4 = {0.f, 0.f, 0.f, 0.f};
    f32x4 acc[4][4];
    #pragma unroll
    for (int mi = 0; mi < 4; ++mi)
        #pragma unroll
        for (int ni = 0; ni < 4; ++ni) acc[mi][ni] = z4;

    #pragma unroll
    for (int ks = 0; ks < 4; ++ks) {
        bf16x8 av[4], bv[4];
        #pragma unroll
        for (int mi = 0; mi < 4; ++mi)
            av[mi] = *(const bf16x8*)&sA[(mi * 16 + lr) * 136 + ks * 32 + kq];
        #pragma unroll
        for (int ni = 0; ni < 4; ++ni)
            bv[ni] = *(const bf16x8*)&W1t[(size_t)(bcol + ni * 16 + lr) * HID + ks * 32 + kq];
        #pragma unroll
        for (int mi = 0; mi < 4; ++mi)
            #pragma unroll
            for (int ni = 0; ni < 4; ++ni)
                acc[mi][ni] = __builtin_amdgcn_mfma_f32_16x16x32_bf16(av[mi], bv[ni],
                                                                      acc[mi][ni], 0, 0, 0);
    }

    float* outp = (bcol < 128) ? P : Q;
    const int cb = bcol & 127;
    const int rq = (lane >> 4) * 4;
    #pragma unroll
    for (int ni = 0; ni < 4; ++ni) {
        const int c = cb + ni * 16 + lr;
        const float bias = (bcol >= 128) ? b1[c] : 0.f;
        #pragma unroll
        for (int mi = 0; mi < 4; ++mi) {
            #pragma unroll
            for (int r = 0; r < 4; ++r) {
                const int gr = n0 + mi * 16 + rq + r;
                if (gr < N_NODES) outp[(size_t)gr * HID + c] = acc[mi][ni][r] + bias;
            }
        }
    }
}

// ---------------- aggH[n] = sum_e relu(P[src_e] + Q[n] + attr_e * w1last) ----------------
__global__ void k_agg(const float* __restrict__ P, const float* __restrict__ Q,
                      const int* __restrict__ row_ptr, const int* __restrict__ s_src,
                      const float* __restrict__ s_attr, const float* __restrict__ w1last,
                      float* __restrict__ aggH) {
    const int n = blockIdx.x * 8 + (threadIdx.x >> 5);
    const int c0 = (threadIdx.x & 31) * 4;
    if (n >= N_NODES) return;
    const float4 q  = *(const float4*)&Q[(size_t)n * HID + c0];
    const float4 wl = *(const float4*)&w1last[c0];
    float4 acc = make_float4(0.f, 0.f, 0.f, 0.f);
    const int lo = row_ptr[n], hi = row_ptr[n + 1];
    for (int e = lo; e < hi; ++e) {
        const int s = s_src[e];
        const float a = s_attr[e];
        const float4 p = *(const float4*)&P[(size_t)s * HID + c0];
        acc.x += fmaxf(fmaf(a, wl.x, p.x + q.x), 0.f);
        acc.y += fmaxf(fmaf(a, wl.y, p.y + q.y), 0.f);
        acc.z += fmaxf(fmaf(a, wl.z, p.z + q.z), 0.f);
        acc.w += fmaxf(fmaf(a, wl.w, p.w + q.w), 0.f);
    }
    *(float4*)&aggH[(size_t)n * HID + c0] = acc;
}

// ------- h += relu(h@U1t^T + aggH@W2Ut^T + ub1 + deg*b2u) @ U2t^T + ub2 (MFMA) -------
__launch_bounds__(256, 3)
__global__ void k_node_upd(float* __restrict__ h, const float* __restrict__ aggH,
                           const bf16* __restrict__ U1t, const bf16* __restrict__ W2Ut,
                           const float* __restrict__ ub1, const float* __restrict__ b2u,
                           const float* __restrict__ degf,
                           const bf16* __restrict__ U2t, const float* __restrict__ ub2) {
    __shared__ bf16 sA[64 * 136];   // h tile; reused for relu'd T tile
    __shared__ bf16 sG[64 * 136];   // aggH tile
    __shared__ float sDeg[64];
    const int tid = threadIdx.x;
    const int n0 = blockIdx.x * 64;
    {
        const int r = tid & 63, cg = tid >> 6;
        const bool valid = (n0 + r) < N_NODES;
        if (cg == 0) sDeg[r] = valid ? degf[n0 + r] : 0.f;
        const float4* srcH = (const float4*)(h + (size_t)(n0 + r) * HID + cg * 32);
        const float4* srcG = (const float4*)(aggH + (size_t)(n0 + r) * HID + cg * 32);
        #pragma unroll
        for (int i = 0; i < 4; ++i) {
            float4 a = valid ? srcH[2 * i] : make_float4(0.f, 0.f, 0.f, 0.f);
            float4 b = valid ? srcH[2 * i + 1] : make_float4(0.f, 0.f, 0.f, 0.f);
            bf16x8 v;
            v[0] = (bf16)a.x; v[1] = (bf16)a.y; v[2] = (bf16)a.z; v[3] = (bf16)a.w;
            v[4] = (bf16)b.x; v[5] = (bf16)b.y; v[6] = (bf16)b.z; v[7] = (bf16)b.w;
            *(bf16x8*)&sA[r * 136 + cg * 32 + i * 8] = v;
            a = valid ? srcG[2 * i] : make_float4(0.f, 0.f, 0.f, 0.f);
            b = valid ? srcG[2 * i + 1] : make_float4(0.f, 0.f, 0.f, 0.f);
            v[0] = (bf16)a.x; v[1] = (bf16)a.y; v[2] = (bf16)a.z; v[3] = (bf16)a.w;
            v[4] = (bf16)b.x; v[5] = (bf16)b.y; v[6] = (bf16)b.z; v[7] = (bf16)b.w;
            *(bf16x8*)&sG[r * 136 + cg * 32 + i * 8] = v;
        }
    }
    __syncthreads();
    const int lane = tid & 63, wave = tid >> 6;
    const int lr = lane & 15, kq = (lane >> 4) * 8;
    const int rq = (lane >> 4) * 4;
    const int nw = wave * 32;

    const f32x4 z4 = {0.f, 0.f, 0.f, 0.f};
    f32x4 acc[4][2];
    #pragma unroll
    for (int mi = 0; mi < 4; ++mi) { acc[mi][0] = z4; acc[mi][1] = z4; }

    #pragma unroll
    for (int ks = 0; ks < 4; ++ks) {
        bf16x8 av[4], bv[2];
        #pragma unroll
        for (int mi = 0; mi < 4; ++mi)
            av[mi] = *(const bf16x8*)&sA[(mi * 16 + lr) * 136 + ks * 32 + kq];
        #pragma unroll
        for (int ni = 0; ni < 2; ++ni)
            bv[ni] = *(const bf16x8*)&U1t[(size_t)(nw + ni * 16 + lr) * HID + ks * 32 + kq];
        #pragma unroll
        for (int mi = 0; mi < 4; ++mi)
            #pragma unroll
            for (int ni = 0; ni < 2; ++ni)
                acc[mi][ni] = __builtin_amdgcn_mfma_f32_16x16x32_bf16(av[mi], bv[ni],
                                                                      acc[mi][ni], 0, 0, 0);
    }
    #pragma unroll
    for (int ks = 0; ks < 4; ++ks) {
        bf16x8 av[4], bv[2];
        #pragma unroll
        for (int mi = 0; mi < 4; ++mi)
            av[mi] = *(const bf16x8*)&sG[(mi * 16 + lr) * 136 + ks * 32 + kq];
        #pragma unroll
        for (int ni = 0; ni < 2; ++ni)
            bv[ni] = *(const bf16x8*)&W2Ut[(size_t)(nw + ni * 16 + lr) * HID + ks * 32 + kq];
        #pragma unroll
        for (int mi = 0; mi < 4; ++mi)
            #pragma unroll
            for (int ni = 0; ni < 2; ++ni)
                acc[mi][ni] = __builtin_amdgcn_mfma_f32_16x16x32_bf16(av[mi], bv[ni],
                                                                      acc[mi][ni], 0, 0, 0);
    }

    __syncthreads();  // everyone done reading sA/sG
    #pragma unroll
    for (int ni = 0; ni < 2; ++ni) {
        const int c = nw + ni * 16 + lr;
        const float bb1 = ub1[c], bb2 = b2u[c];
        #pragma unroll
        for (int mi = 0; mi < 4; ++mi) {
            #pragma unroll
            for (int r = 0; r < 4; ++r) {
                const int row = mi * 16 + rq + r;
                float v = acc[mi][ni][r] + bb1 + sDeg[row] * bb2;
                sA[row * 136 + c] = (bf16)fmaxf(v, 0.f);
            }
        }
    }
    __syncthreads();

    f32x4 acc2[4][2];
    #pragma unroll
    for (int mi = 0; mi < 4; ++mi) { acc2[mi][0] = z4; acc2[mi][1] = z4; }
    #pragma unroll
    for (int ks = 0; ks < 4; ++ks) {
        bf16x8 av[4], bv[2];
        #pragma unroll
        for (int mi = 0; mi < 4; ++mi)
            av[mi] = *(const bf16x8*)&sA[(mi * 16 + lr) * 136 + ks * 32 + kq];
        #pragma unroll
        for (int ni = 0; ni < 2; ++ni)
            bv[ni] = *(const bf16x8*)&U2t[(size_t)(nw + ni * 16 + lr) * HID + ks * 32 + kq];
        #pragma unroll
        for (int mi = 0; mi < 4; ++mi)
            #pragma unroll
            for (int ni = 0; ni < 2; ++ni)
                acc2[mi][ni] = __builtin_amdgcn_mfma_f32_16x16x32_bf16(av[mi], bv[ni],
                                                                       acc2[mi][ni], 0, 0, 0);
    }

    #pragma unroll
    for (int ni = 0; ni < 2; ++ni) {
        const int c = nw + ni * 16 + lr;
        const float bb = ub2[c];
        #pragma unroll
        for (int mi = 0; mi < 4; ++mi) {
            #pragma unroll
            for (int r = 0; r < 4; ++r) {
                const int gr = n0 + mi * 16 + rq + r;
                if (gr < N_NODES) {
                    const size_t off = (size_t)gr * HID + c;
                    h[off] += acc2[mi][ni][r] + bb;
                }
            }
        }
    }
}

// ---------------- pooling (batch is sorted) ----------------
__device__ inline int lb(const int* a, int n, int v) {
    int lo = 0, hi = n;
    while (lo < hi) { int m = (lo + hi) >> 1; if (a[m] < v) lo = m + 1; else hi = m; }
    return lo;
}

__global__ void k_pool(const float* __restrict__ h, const int* __restrict__ batch,
                       float* __restrict__ pooled, float* __restrict__ counts) {
    const int g = blockIdx.x >> 2, part = blockIdx.x & 3;
    __shared__ int sb[2];
    if (threadIdx.x == 0) { sb[0] = lb(batch, N_NODES, g); sb[1] = lb(batch, N_NODES, g + 1); }
    __syncthreads();
    const int lo = sb[0], hi = sb[1], cnt = hi - lo;
    if (threadIdx.x == 0 && part == 0) counts[g] = (float)cnt;
    const int per = (cnt + 3) >> 2;
    const int a = lo + part * per;
    const int b = min(a + per, hi);
    const int c = threadIdx.x;
    float s = 0.f;
    for (int n = a; n < b; ++n) s += h[(size_t)n * HID + c];
    if (b > a) atomicAdd(&pooled[g * HID + c], s);
}

// ---------------- head MLP (fp32) ----------------
__global__ void k_head(const float* __restrict__ pooled, const float* __restrict__ counts,
                       const float* __restrict__ hw1, const float* __restrict__ hb1,
                       const float* __restrict__ hw2, const float* __restrict__ hb2,
                       float* __restrict__ out) {
    const int g = blockIdx.x;
    const int c = threadIdx.x;
    __shared__ float sp[HID];
    __shared__ float red[HID];
    const float cnt = fmaxf(counts[g], 1.f);
    sp[c] = pooled[g * HID + c] / cnt;
    __syncthreads();
    float acc = hb1[c];
    #pragma unroll 8
    for (int k = 0; k < HID; ++k) acc = fmaf(sp[k], hw1[k * HID + c], acc);
    red[c] = fmaxf(acc, 0.f) * hw2[c];
    __syncthreads();
    for (int s = 64; s > 0; s >>= 1) {
        if (c < s) red[c] += red[c + s];
        __syncthreads();
    }
    if (c == 0) out[g] = red[0] + hb2[0];
}

extern "C" void kernel_launch(void* const* d_in, const int* in_sizes, int n_in,
                              void* d_out, int out_size, void* d_ws, size_t ws_size,
                              hipStream_t stream) {
    const int*   z       = (const int*)d_in[0];
    const int*   ei      = (const int*)d_in[1];
    const float* eattr   = (const float*)d_in[2];
    const int*   batch   = (const int*)d_in[3];
    const float* embed   = (const float*)d_in[4];
    const float* msg_w1  = (const float*)d_in[5];
    const float* msg_b1  = (const float*)d_in[6];
    const float* msg_w2  = (const float*)d_in[7];
    const float* msg_b2  = (const float*)d_in[8];
    const float* upd_w1  = (const float*)d_in[9];
    const float* upd_b1  = (const float*)d_in[10];
    const float* upd_w2  = (const float*)d_in[11];
    const float* upd_b2  = (const float*)d_in[12];
    const float* head_w1 = (const float*)d_in[13];
    const float* head_b1 = (const float*)d_in[14];
    const float* head_w2 = (const float*)d_in[15];
    const float* head_b2 = (const float*)d_in[16];
    float* out = (float*)d_out;

    // workspace layout (~107 MB)
    float* h      = (float*)d_ws;
    float* P      = h + (size_t)N_NODES * HID;
    float* Q      = P + (size_t)N_NODES * HID;
    float* aggH   = Q + (size_t)N_NODES * HID;
    float* pooled = aggH + (size_t)N_NODES * HID;
    float* counts = pooled + NUM_GRAPHS * HID;
    float* b2u    = counts + NUM_GRAPHS;
    float* s_attr = b2u + HID;
    float* degf   = s_attr + N_EDGES;
    int* deg_i    = (int*)(degf + N_NODES);
    int* row_ptr  = deg_i + N_NODES;
    int* partial  = row_ptr + N_NODES + 1;
    int* cursor   = partial + 256;
    int* s_src    = cursor + N_NODES;
    bf16* W1t     = (bf16*)((((unsigned long long)(s_src + N_EDGES)) + 15ULL) & ~15ULL);
    bf16* U1t     = W1t + 256 * HID;
    bf16* W2Ut    = U1t + HID * HID;
    bf16* U2t     = W2Ut + HID * HID;

    const int* esrc = ei;
    const int* edst = ei + N_EDGES;

    k_embed<<<(N_NODES * 32 + 255) / 256, 256, 0, stream>>>(z, (const float4*)embed, (float4*)h);

    // CSR build (per call; deterministic sums not required beyond fp tolerance)
    hipMemsetAsync(deg_i, 0, N_NODES * sizeof(int), stream);
    k_hist<<<(N_EDGES + 255) / 256, 256, 0, stream>>>(edst, deg_i);
    k_scan1<<<SCAN_B, 256, 0, stream>>>(deg_i, partial);
    k_scan2<<<1, 256, 0, stream>>>(partial, row_ptr);
    k_scan3<<<SCAN_B, 256, 0, stream>>>(deg_i, partial, row_ptr, cursor, degf);
    k_scatter<<<(N_EDGES + 255) / 256, 256, 0, stream>>>(esrc, edst, eattr, cursor, s_src, s_attr);

    const int nblk = (N_NODES + 63) / 64;
    for (int l = 0; l < 3; ++l) {
        const float* w1 = msg_w1 + (size_t)l * 257 * HID;
        const float* uw1 = upd_w1 + (size_t)l * 2 * HID * HID;
        k_wprep<<<512, 128, 0, stream>>>(w1, uw1, upd_w2 + (size_t)l * HID * HID,
                                         W1t, U1t, U2t);
        k_small<<<HID + 1, HID, 0, stream>>>(
            msg_w2 + (size_t)l * HID * HID, uw1, msg_b2 + (size_t)l * HID, W2Ut, b2u);
        k_node_pre<<<nblk, 256, 0, stream>>>(h, W1t, msg_b1 + (size_t)l * HID, P, Q);
        k_agg<<<(N_NODES + 7) / 8, 256, 0, stream>>>(
            P, Q, row_ptr, s_src, s_attr, w1 + 256 * HID, aggH);
        k_node_upd<<<nblk, 256, 0, stream>>>(
            h, aggH, U1t, W2Ut, upd_b1 + (size_t)l * HID, b2u, degf,
            U2t, upd_b2 + (size_t)l * HID);
    }
    hipMemsetAsync(pooled, 0, (NUM_GRAPHS * HID + NUM_GRAPHS) * sizeof(float), stream);
    k_pool<<<NUM_GRAPHS * 4, 128, 0, stream>>>(h, batch, pooled, counts);
    k_head<<<NUM_GRAPHS, 128, 0, stream>>>(pooled, counts, head_w1, head_b1, head_w2, head_b2, out);
}

// Round 4
// 493.500 us; speedup vs baseline: 10.1146x; 1.1443x over previous
//
#include <hip/hip_runtime.h>

#define N_NODES 50000
#define NPAD 50048          // 782 * 64, row-padded so tile reads never fault
#define N_EDGES 400000
#define HID 128
#define NUM_GRAPHS 64
#define SCAN_B 196  // ceil(N_NODES/256)

typedef __bf16 bf16;
typedef bf16 bf16x8 __attribute__((ext_vector_type(8)));
typedef bf16 bf16x4 __attribute__((ext_vector_type(4)));
typedef float f32x4 __attribute__((ext_vector_type(4)));

__device__ inline bf16x8 cvt8(const float* p) {
    const float4 a = *(const float4*)p;
    const float4 b = *(const float4*)(p + 4);
    bf16x8 v;
    v[0] = (bf16)a.x; v[1] = (bf16)a.y; v[2] = (bf16)a.z; v[3] = (bf16)a.w;
    v[4] = (bf16)b.x; v[5] = (bf16)b.y; v[6] = (bf16)b.z; v[7] = (bf16)b.w;
    return v;
}

// ---------------- embed gather: h = embed[z] ----------------
__global__ void k_embed(const int* __restrict__ z, const float4* __restrict__ embed4,
                        float4* __restrict__ h4) {
    int idx = blockIdx.x * 256 + threadIdx.x;
    if (idx >= N_NODES * 32) return;
    int node = idx >> 5;
    int c = idx & 31;
    h4[idx] = embed4[(size_t)z[node] * 32 + c];
}

// ---------------- CSR build ----------------
__global__ void k_hist(const int* __restrict__ edst, int* __restrict__ deg) {
    int e = blockIdx.x * 256 + threadIdx.x;
    if (e < N_EDGES) atomicAdd(&deg[edst[e]], 1);
}

__global__ void k_scan1(const int* __restrict__ deg, int* __restrict__ partial) {
    __shared__ int buf[256];
    int i = blockIdx.x * 256 + threadIdx.x;
    buf[threadIdx.x] = (i < N_NODES) ? deg[i] : 0;
    __syncthreads();
    for (int off = 128; off > 0; off >>= 1) {
        if (threadIdx.x < off) buf[threadIdx.x] += buf[threadIdx.x + off];
        __syncthreads();
    }
    if (threadIdx.x == 0) partial[blockIdx.x] = buf[0];
}

__global__ void k_scan2(int* __restrict__ partial, int* __restrict__ row_ptr) {
    __shared__ int buf[256];
    int v = (threadIdx.x < SCAN_B) ? partial[threadIdx.x] : 0;
    buf[threadIdx.x] = v;
    __syncthreads();
    for (int off = 1; off < 256; off <<= 1) {
        int t = (threadIdx.x >= off) ? buf[threadIdx.x - off] : 0;
        __syncthreads();
        buf[threadIdx.x] += t;
        __syncthreads();
    }
    if (threadIdx.x < SCAN_B) partial[threadIdx.x] = buf[threadIdx.x] - v;  // exclusive
    if (threadIdx.x == 255) row_ptr[N_NODES] = buf[255];
}

__global__ void k_scan3(const int* __restrict__ deg, const int* __restrict__ partial,
                        int* __restrict__ row_ptr, int* __restrict__ cursor,
                        float* __restrict__ degf) {
    __shared__ int buf[256];
    int i = blockIdx.x * 256 + threadIdx.x;
    int v = (i < N_NODES) ? deg[i] : 0;
    buf[threadIdx.x] = v;
    __syncthreads();
    for (int off = 1; off < 256; off <<= 1) {
        int t = (threadIdx.x >= off) ? buf[threadIdx.x - off] : 0;
        __syncthreads();
        buf[threadIdx.x] += t;
        __syncthreads();
    }
    if (i < N_NODES) {
        int ex = partial[blockIdx.x] + buf[threadIdx.x] - v;
        row_ptr[i] = ex;
        cursor[i] = ex;
        degf[i] = (float)v;
    }
}

__global__ void k_scatter(const int* __restrict__ esrc, const int* __restrict__ edst,
                          const float* __restrict__ attr, int* __restrict__ cursor,
                          int* __restrict__ s_src, float* __restrict__ s_attr) {
    int e = blockIdx.x * 256 + threadIdx.x;
    if (e >= N_EDGES) return;
    int p = atomicAdd(&cursor[edst[e]], 1);
    s_src[p] = esrc[e];
    s_attr[p] = attr[e];
}

// ---------------- weight prep (all layers upfront): bf16 [n][k] transposes ----------------
__global__ void k_wprep(const float* __restrict__ msg_w1, const float* __restrict__ upd_w1,
                        const float* __restrict__ upd_w2,
                        bf16* __restrict__ W1t, bf16* __restrict__ U1t,
                        bf16* __restrict__ U2t) {
    const int l = blockIdx.y;
    const int n = blockIdx.x, k = threadIdx.x;
    const float* w1  = msg_w1 + (size_t)l * 257 * HID;
    const float* uw1 = upd_w1 + (size_t)l * 2 * HID * HID;
    const float* uw2 = upd_w2 + (size_t)l * HID * HID;
    if (n < 256) {
        W1t[(size_t)l * 256 * HID + n * HID + k] =
            (bf16)w1[(size_t)((n & 128) + k) * HID + (n & 127)];
    } else if (n < 384) {
        const int nn = n - 256;
        U1t[(size_t)l * HID * HID + nn * HID + k] = (bf16)uw1[(size_t)k * HID + nn];
    } else {
        const int nn = n - 384;
        U2t[(size_t)l * HID * HID + nn * HID + k] = (bf16)uw2[(size_t)k * HID + nn];
    }
}

// ---------------- W2Ut[l][j][k] = (w2 @ uw1_bot)[k][j]; b2u[l] = b2 @ uw1_bot ----------------
__global__ void k_small(const float* __restrict__ msg_w2, const float* __restrict__ upd_w1,
                        const float* __restrict__ msg_b2,
                        bf16* __restrict__ W2Ut, float* __restrict__ b2u) {
    __shared__ float row[HID];
    const int l = blockIdx.y;
    const int k = blockIdx.x, j = threadIdx.x;
    const float* w2  = msg_w2 + (size_t)l * HID * HID;
    const float* uw1 = upd_w1 + (size_t)l * 2 * HID * HID;
    const float* b2  = msg_b2 + (size_t)l * HID;
    const float* src = (k < HID) ? &w2[(size_t)k * HID] : b2;
    row[j] = src[j];
    __syncthreads();
    float acc = 0.f;
    #pragma unroll 8
    for (int m = 0; m < HID; ++m)
        acc = fmaf(row[m], uw1[(size_t)(HID + m) * HID + j], acc);
    if (k < HID) W2Ut[(size_t)l * HID * HID + (size_t)j * HID + k] = (bf16)acc;
    else b2u[l * HID + j] = acc;
}

// ---------------- [P|Q] = h @ W1t^T (MFMA, no LDS); Q gets +b1 ----------------
__launch_bounds__(256, 4)
__global__ void k_node_pre(const float* __restrict__ h, const bf16* __restrict__ W1t,
                           const float* __restrict__ b1,
                           bf16* __restrict__ P, bf16* __restrict__ Q) {
    const int tid = threadIdx.x;
    const int n0 = blockIdx.x * 64;
    const int lane = tid & 63, wave = tid >> 6;
    const int lr = lane & 15, kq = (lane >> 4) * 8;
    const int bcol = wave * 64;

    const f32x4 z4 = {0.f, 0.f, 0.f, 0.f};
    f32x4 acc[4][4];
    #pragma unroll
    for (int mi = 0; mi < 4; ++mi)
        #pragma unroll
        for (int ni = 0; ni < 4; ++ni) acc[mi][ni] = z4;

    #pragma unroll
    for (int ks = 0; ks < 4; ++ks) {
        bf16x8 av[4], bv[4];
        #pragma unroll
        for (int mi = 0; mi < 4; ++mi)
            av[mi] = cvt8(&h[(size_t)(n0 + mi * 16 + lr) * HID + ks * 32 + kq]);
        #pragma unroll
        for (int ni = 0; ni < 4; ++ni)
            bv[ni] = *(const bf16x8*)&W1t[(size_t)(bcol + ni * 16 + lr) * HID + ks * 32 + kq];
        #pragma unroll
        for (int mi = 0; mi < 4; ++mi)
            #pragma unroll
            for (int ni = 0; ni < 4; ++ni)
                acc[mi][ni] = __builtin_amdgcn_mfma_f32_16x16x32_bf16(av[mi], bv[ni],
                                                                      acc[mi][ni], 0, 0, 0);
    }

    bf16* outp = (bcol < 128) ? P : Q;
    const int cb = bcol & 127;
    const int rq = (lane >> 4) * 4;
    #pragma unroll
    for (int ni = 0; ni < 4; ++ni) {
        const int c = cb + ni * 16 + lr;
        const float bias = (bcol >= 128) ? b1[c] : 0.f;
        #pragma unroll
        for (int mi = 0; mi < 4; ++mi) {
            #pragma unroll
            for (int r = 0; r < 4; ++r) {
                const int gr = n0 + mi * 16 + rq + r;
                if (gr < N_NODES) outp[(size_t)gr * HID + c] = (bf16)(acc[mi][ni][r] + bias);
            }
        }
    }
}

// ---------------- aggH[n] = sum_e relu(P[src_e] + Q[n] + attr_e * w1last)  (bf16 io) -------
__global__ void k_agg(const bf16* __restrict__ P, const bf16* __restrict__ Q,
                      const int* __restrict__ row_ptr, const int* __restrict__ s_src,
                      const float* __restrict__ s_attr, const float* __restrict__ w1last,
                      bf16* __restrict__ aggH) {
    const int n = blockIdx.x * 8 + (threadIdx.x >> 5);
    const int c0 = (threadIdx.x & 31) * 4;
    if (n >= N_NODES) return;
    const bf16x4 qb = *(const bf16x4*)&Q[(size_t)n * HID + c0];
    const float4 wl = *(const float4*)&w1last[c0];
    const float qx = (float)qb[0], qy = (float)qb[1], qz = (float)qb[2], qw = (float)qb[3];
    float ax = 0.f, ay = 0.f, az = 0.f, aw = 0.f;
    const int lo = row_ptr[n], hi = row_ptr[n + 1];
    for (int e = lo; e < hi; ++e) {
        const int s = s_src[e];
        const float a = s_attr[e];
        const bf16x4 pb = *(const bf16x4*)&P[(size_t)s * HID + c0];
        ax += fmaxf(fmaf(a, wl.x, (float)pb[0] + qx), 0.f);
        ay += fmaxf(fmaf(a, wl.y, (float)pb[1] + qy), 0.f);
        az += fmaxf(fmaf(a, wl.z, (float)pb[2] + qz), 0.f);
        aw += fmaxf(fmaf(a, wl.w, (float)pb[3] + qw), 0.f);
    }
    bf16x4 o;
    o[0] = (bf16)ax; o[1] = (bf16)ay; o[2] = (bf16)az; o[3] = (bf16)aw;
    *(bf16x4*)&aggH[(size_t)n * HID + c0] = o;
}

// ------- h += relu(h@U1t^T + aggH@W2Ut^T + ub1 + deg*b2u) @ U2t^T + ub2 (MFMA) -------
__launch_bounds__(256, 4)
__global__ void k_node_upd(float* __restrict__ h, const bf16* __restrict__ aggH,
                           const bf16* __restrict__ U1t, const bf16* __restrict__ W2Ut,
                           const float* __restrict__ ub1, const float* __restrict__ b2u,
                           const float* __restrict__ degf,
                           const bf16* __restrict__ U2t, const float* __restrict__ ub2) {
    __shared__ bf16 sT[64 * 136];   // relu'd intermediate tile, +8 pad
    const int tid = threadIdx.x;
    const int n0 = blockIdx.x * 64;
    const int lane = tid & 63, wave = tid >> 6;
    const int lr = lane & 15, kq = (lane >> 4) * 8;
    const int rq = (lane >> 4) * 4;
    const int nw = wave * 32;

    const f32x4 z4 = {0.f, 0.f, 0.f, 0.f};
    f32x4 acc[4][2];
    #pragma unroll
    for (int mi = 0; mi < 4; ++mi) { acc[mi][0] = z4; acc[mi][1] = z4; }

    // GEMM1a: h @ U1t^T  (A direct from global fp32 -> cvt)
    #pragma unroll
    for (int ks = 0; ks < 4; ++ks) {
        bf16x8 av[4], bv[2];
        #pragma unroll
        for (int mi = 0; mi < 4; ++mi)
            av[mi] = cvt8(&h[(size_t)(n0 + mi * 16 + lr) * HID + ks * 32 + kq]);
        #pragma unroll
        for (int ni = 0; ni < 2; ++ni)
            bv[ni] = *(const bf16x8*)&U1t[(size_t)(nw + ni * 16 + lr) * HID + ks * 32 + kq];
        #pragma unroll
        for (int mi = 0; mi < 4; ++mi)
            #pragma unroll
            for (int ni = 0; ni < 2; ++ni)
                acc[mi][ni] = __builtin_amdgcn_mfma_f32_16x16x32_bf16(av[mi], bv[ni],
                                                                      acc[mi][ni], 0, 0, 0);
    }
    // GEMM1b: aggH @ W2Ut^T  (A direct from global bf16)
    #pragma unroll
    for (int ks = 0; ks < 4; ++ks) {
        bf16x8 av[4], bv[2];
        #pragma unroll
        for (int mi = 0; mi < 4; ++mi)
            av[mi] = *(const bf16x8*)&aggH[(size_t)(n0 + mi * 16 + lr) * HID + ks * 32 + kq];
        #pragma unroll
        for (int ni = 0; ni < 2; ++ni)
            bv[ni] = *(const bf16x8*)&W2Ut[(size_t)(nw + ni * 16 + lr) * HID + ks * 32 + kq];
        #pragma unroll
        for (int mi = 0; mi < 4; ++mi)
            #pragma unroll
            for (int ni = 0; ni < 2; ++ni)
                acc[mi][ni] = __builtin_amdgcn_mfma_f32_16x16x32_bf16(av[mi], bv[ni],
                                                                      acc[mi][ni], 0, 0, 0);
    }

    // bias + deg*b2u + relu -> sT (bf16)
    #pragma unroll
    for (int ni = 0; ni < 2; ++ni) {
        const int c = nw + ni * 16 + lr;
        const float bb1 = ub1[c], bb2 = b2u[c];
        #pragma unroll
        for (int mi = 0; mi < 4; ++mi) {
            #pragma unroll
            for (int r = 0; r < 4; ++r) {
                const int row = mi * 16 + rq + r;
                const float dg = degf[n0 + row];   // NPAD-padded, garbage rows masked at store
                float v = acc[mi][ni][r] + bb1 + dg * bb2;
                sT[row * 136 + c] = (bf16)fmaxf(v, 0.f);
            }
        }
    }
    __syncthreads();

    // GEMM2: sT @ U2t^T
    f32x4 acc2[4][2];
    #pragma unroll
    for (int mi = 0; mi < 4; ++mi) { acc2[mi][0] = z4; acc2[mi][1] = z4; }
    #pragma unroll
    for (int ks = 0; ks < 4; ++ks) {
        bf16x8 av[4], bv[2];
        #pragma unroll
        for (int mi = 0; mi < 4; ++mi)
            av[mi] = *(const bf16x8*)&sT[(mi * 16 + lr) * 136 + ks * 32 + kq];
        #pragma unroll
        for (int ni = 0; ni < 2; ++ni)
            bv[ni] = *(const bf16x8*)&U2t[(size_t)(nw + ni * 16 + lr) * HID + ks * 32 + kq];
        #pragma unroll
        for (int mi = 0; mi < 4; ++mi)
            #pragma unroll
            for (int ni = 0; ni < 2; ++ni)
                acc2[mi][ni] = __builtin_amdgcn_mfma_f32_16x16x32_bf16(av[mi], bv[ni],
                                                                       acc2[mi][ni], 0, 0, 0);
    }

    #pragma unroll
    for (int ni = 0; ni < 2; ++ni) {
        const int c = nw + ni * 16 + lr;
        const float bb = ub2[c];
        #pragma unroll
        for (int mi = 0; mi < 4; ++mi) {
            #pragma unroll
            for (int r = 0; r < 4; ++r) {
                const int gr = n0 + mi * 16 + rq + r;
                if (gr < N_NODES) h[(size_t)gr * HID + c] += acc2[mi][ni][r] + bb;
            }
        }
    }
}

// ---------------- pooling (batch is sorted) ----------------
__device__ inline int lb(const int* a, int n, int v) {
    int lo = 0, hi = n;
    while (lo < hi) { int m = (lo + hi) >> 1; if (a[m] < v) lo = m + 1; else hi = m; }
    return lo;
}

__global__ void k_pool(const float* __restrict__ h, const int* __restrict__ batch,
                       float* __restrict__ pooled, float* __restrict__ counts) {
    const int g = blockIdx.x >> 2, part = blockIdx.x & 3;
    __shared__ int sb[2];
    if (threadIdx.x == 0) { sb[0] = lb(batch, N_NODES, g); sb[1] = lb(batch, N_NODES, g + 1); }
    __syncthreads();
    const int lo = sb[0], hi = sb[1], cnt = hi - lo;
    if (threadIdx.x == 0 && part == 0) counts[g] = (float)cnt;
    const int per = (cnt + 3) >> 2;
    const int a = lo + part * per;
    const int b = min(a + per, hi);
    const int c = threadIdx.x;
    float s = 0.f;
    for (int n = a; n < b; ++n) s += h[(size_t)n * HID + c];
    if (b > a) atomicAdd(&pooled[g * HID + c], s);
}

// ---------------- head MLP (fp32) ----------------
__global__ void k_head(const float* __restrict__ pooled, const float* __restrict__ counts,
                       const float* __restrict__ hw1, const float* __restrict__ hb1,
                       const float* __restrict__ hw2, const float* __restrict__ hb2,
                       float* __restrict__ out) {
    const int g = blockIdx.x;
    const int c = threadIdx.x;
    __shared__ float sp[HID];
    __shared__ float red[HID];
    const float cnt = fmaxf(counts[g], 1.f);
    sp[c] = pooled[g * HID + c] / cnt;
    __syncthreads();
    float acc = hb1[c];
    #pragma unroll 8
    for (int k = 0; k < HID; ++k) acc = fmaf(sp[k], hw1[k * HID + c], acc);
    red[c] = fmaxf(acc, 0.f) * hw2[c];
    __syncthreads();
    for (int s = 64; s > 0; s >>= 1) {
        if (c < s) red[c] += red[c + s];
        __syncthreads();
    }
    if (c == 0) out[g] = red[0] + hb2[0];
}

extern "C" void kernel_launch(void* const* d_in, const int* in_sizes, int n_in,
                              void* d_out, int out_size, void* d_ws, size_t ws_size,
                              hipStream_t stream) {
    const int*   z       = (const int*)d_in[0];
    const int*   ei      = (const int*)d_in[1];
    const float* eattr   = (const float*)d_in[2];
    const int*   batch   = (const int*)d_in[3];
    const float* embed   = (const float*)d_in[4];
    const float* msg_w1  = (const float*)d_in[5];
    const float* msg_b1  = (const float*)d_in[6];
    const float* msg_w2  = (const float*)d_in[7];
    const float* msg_b2  = (const float*)d_in[8];
    const float* upd_w1  = (const float*)d_in[9];
    const float* upd_b1  = (const float*)d_in[10];
    const float* upd_w2  = (const float*)d_in[11];
    const float* upd_b2  = (const float*)d_in[12];
    const float* head_w1 = (const float*)d_in[13];
    const float* head_b1 = (const float*)d_in[14];
    const float* head_w2 = (const float*)d_in[15];
    const float* head_b2 = (const float*)d_in[16];
    float* out = (float*)d_out;

    // workspace layout (~70 MB)
    float* h      = (float*)d_ws;                       // NPAD x 128 fp32
    float* pooled = h + (size_t)NPAD * HID;
    float* counts = pooled + NUM_GRAPHS * HID;
    float* b2u    = counts + NUM_GRAPHS;                // 3 x 128
    float* s_attr = b2u + 3 * HID;
    float* degf   = s_attr + N_EDGES;                   // NPAD
    int* deg_i    = (int*)(degf + NPAD);
    int* row_ptr  = deg_i + N_NODES;
    int* partial  = row_ptr + N_NODES + 1;
    int* cursor   = partial + 256;
    int* s_src    = cursor + N_NODES;
    bf16* P       = (bf16*)((((unsigned long long)(s_src + N_EDGES)) + 15ULL) & ~15ULL);
    bf16* Q       = P + (size_t)NPAD * HID;
    bf16* aggH    = Q + (size_t)NPAD * HID;
    bf16* W1t     = aggH + (size_t)NPAD * HID;          // 3 x 256 x 128
    bf16* U1t     = W1t + 3 * 256 * HID;                // 3 x 128 x 128
    bf16* W2Ut    = U1t + 3 * HID * HID;
    bf16* U2t     = W2Ut + 3 * HID * HID;

    const int* esrc = ei;
    const int* edst = ei + N_EDGES;

    k_embed<<<(N_NODES * 32 + 255) / 256, 256, 0, stream>>>(z, (const float4*)embed, (float4*)h);

    // CSR build + all-layer weight prep (independent of layer loop)
    hipMemsetAsync(deg_i, 0, N_NODES * sizeof(int), stream);
    k_hist<<<(N_EDGES + 255) / 256, 256, 0, stream>>>(edst, deg_i);
    k_scan1<<<SCAN_B, 256, 0, stream>>>(deg_i, partial);
    k_scan2<<<1, 256, 0, stream>>>(partial, row_ptr);
    k_scan3<<<SCAN_B, 256, 0, stream>>>(deg_i, partial, row_ptr, cursor, degf);
    k_scatter<<<(N_EDGES + 255) / 256, 256, 0, stream>>>(esrc, edst, eattr, cursor, s_src, s_attr);
    {
        dim3 g1(512, 3);
        k_wprep<<<g1, 128, 0, stream>>>(msg_w1, upd_w1, upd_w2, W1t, U1t, U2t);
        dim3 g2(HID + 1, 3);
        k_small<<<g2, HID, 0, stream>>>(msg_w2, upd_w1, msg_b2, W2Ut, b2u);
    }

    const int nblk = NPAD / 64;
    for (int l = 0; l < 3; ++l) {
        const float* w1 = msg_w1 + (size_t)l * 257 * HID;
        k_node_pre<<<nblk, 256, 0, stream>>>(h, W1t + (size_t)l * 256 * HID,
                                             msg_b1 + (size_t)l * HID, P, Q);
        k_agg<<<(N_NODES + 7) / 8, 256, 0, stream>>>(
            P, Q, row_ptr, s_src, s_attr, w1 + 256 * HID, aggH);
        k_node_upd<<<nblk, 256, 0, stream>>>(
            h, aggH, U1t + (size_t)l * HID * HID, W2Ut + (size_t)l * HID * HID,
            upd_b1 + (size_t)l * HID, b2u + l * HID, degf,
            U2t + (size_t)l * HID * HID, upd_b2 + (size_t)l * HID);
    }
    hipMemsetAsync(pooled, 0, (NUM_GRAPHS * HID + NUM_GRAPHS) * sizeof(float), stream);
    k_pool<<<NUM_GRAPHS * 4, 128, 0, stream>>>(h, batch, pooled, counts);
    k_head<<<NUM_GRAPHS, 128, 0, stream>>>(pooled, counts, head_w1, head_b1, head_w2, head_b2, out);
}

// Round 5
// 400.965 us; speedup vs baseline: 12.4489x; 1.2308x over previous
//
#include <hip/hip_runtime.h>

#define N_NODES 50000
#define NPAD 50048          // 782 * 64, row-padded so tile reads never fault
#define N_EDGES 400000
#define HID 128
#define NUM_GRAPHS 64
#define SCAN_B 196  // ceil(N_NODES/256)

typedef __bf16 bf16;
typedef bf16 bf16x8 __attribute__((ext_vector_type(8)));
typedef bf16 bf16x4 __attribute__((ext_vector_type(4)));
typedef float f32x4 __attribute__((ext_vector_type(4)));

__device__ inline bf16x8 cvt8(const float* p) {
    const float4 a = *(const float4*)p;
    const float4 b = *(const float4*)(p + 4);
    bf16x8 v;
    v[0] = (bf16)a.x; v[1] = (bf16)a.y; v[2] = (bf16)a.z; v[3] = (bf16)a.w;
    v[4] = (bf16)b.x; v[5] = (bf16)b.y; v[6] = (bf16)b.z; v[7] = (bf16)b.w;
    return v;
}

// ---------------- embed gather: h16 = bf16(embed[z]); zero pad rows ----------------
__global__ void k_embed(const int* __restrict__ z, const float* __restrict__ embed,
                        bf16* __restrict__ h16) {
    int idx = blockIdx.x * 256 + threadIdx.x;   // over NPAD*16 chunks of 8 channels
    if (idx >= NPAD * 16) return;
    int node = idx >> 4;
    int c8 = (idx & 15) * 8;
    bf16x8 v;
    if (node < N_NODES) {
        v = cvt8(&embed[(size_t)z[node] * HID + c8]);
    } else {
        #pragma unroll
        for (int j = 0; j < 8; ++j) v[j] = (bf16)0.f;
    }
    *(bf16x8*)&h16[(size_t)node * HID + c8] = v;
}

// ---------------- CSR build ----------------
__global__ void k_hist(const int* __restrict__ edst, int* __restrict__ deg) {
    int e = blockIdx.x * 256 + threadIdx.x;
    if (e < N_EDGES) atomicAdd(&deg[edst[e]], 1);
}

__global__ void k_scan1(const int* __restrict__ deg, int* __restrict__ partial) {
    __shared__ int buf[256];
    int i = blockIdx.x * 256 + threadIdx.x;
    buf[threadIdx.x] = (i < N_NODES) ? deg[i] : 0;
    __syncthreads();
    for (int off = 128; off > 0; off >>= 1) {
        if (threadIdx.x < off) buf[threadIdx.x] += buf[threadIdx.x + off];
        __syncthreads();
    }
    if (threadIdx.x == 0) partial[blockIdx.x] = buf[0];
}

__global__ void k_scan2(int* __restrict__ partial, int* __restrict__ row_ptr) {
    __shared__ int buf[256];
    int v = (threadIdx.x < SCAN_B) ? partial[threadIdx.x] : 0;
    buf[threadIdx.x] = v;
    __syncthreads();
    for (int off = 1; off < 256; off <<= 1) {
        int t = (threadIdx.x >= off) ? buf[threadIdx.x - off] : 0;
        __syncthreads();
        buf[threadIdx.x] += t;
        __syncthreads();
    }
    if (threadIdx.x < SCAN_B) partial[threadIdx.x] = buf[threadIdx.x] - v;  // exclusive
    if (threadIdx.x == 255) row_ptr[N_NODES] = buf[255];
}

__global__ void k_scan3(const int* __restrict__ deg, const int* __restrict__ partial,
                        int* __restrict__ row_ptr, int* __restrict__ cursor,
                        float* __restrict__ degf) {
    __shared__ int buf[256];
    int i = blockIdx.x * 256 + threadIdx.x;
    int v = (i < N_NODES) ? deg[i] : 0;
    buf[threadIdx.x] = v;
    __syncthreads();
    for (int off = 1; off < 256; off <<= 1) {
        int t = (threadIdx.x >= off) ? buf[threadIdx.x - off] : 0;
        __syncthreads();
        buf[threadIdx.x] += t;
        __syncthreads();
    }
    if (i < N_NODES) {
        int ex = partial[blockIdx.x] + buf[threadIdx.x] - v;
        row_ptr[i] = ex;
        cursor[i] = ex;
        degf[i] = (float)v;
    }
}

__global__ void k_scatter(const int* __restrict__ esrc, const int* __restrict__ edst,
                          const float* __restrict__ attr, int* __restrict__ cursor,
                          int* __restrict__ s_src, float* __restrict__ s_attr) {
    int e = blockIdx.x * 256 + threadIdx.x;
    if (e >= N_EDGES) return;
    int p = atomicAdd(&cursor[edst[e]], 1);
    s_src[p] = esrc[e];
    s_attr[p] = attr[e];
}

// ---------------- weight prep (all layers upfront): bf16 [n][k] transposes ----------------
__global__ void k_wprep(const float* __restrict__ msg_w1, const float* __restrict__ upd_w1,
                        const float* __restrict__ upd_w2,
                        bf16* __restrict__ W1t, bf16* __restrict__ U1t,
                        bf16* __restrict__ U2t) {
    const int l = blockIdx.y;
    const int n = blockIdx.x, k = threadIdx.x;
    const float* w1  = msg_w1 + (size_t)l * 257 * HID;
    const float* uw1 = upd_w1 + (size_t)l * 2 * HID * HID;
    const float* uw2 = upd_w2 + (size_t)l * HID * HID;
    if (n < 256) {
        W1t[(size_t)l * 256 * HID + n * HID + k] =
            (bf16)w1[(size_t)((n & 128) + k) * HID + (n & 127)];
    } else if (n < 384) {
        const int nn = n - 256;
        U1t[(size_t)l * HID * HID + nn * HID + k] = (bf16)uw1[(size_t)k * HID + nn];
    } else {
        const int nn = n - 384;
        U2t[(size_t)l * HID * HID + nn * HID + k] = (bf16)uw2[(size_t)k * HID + nn];
    }
}

// ---------------- W2Ut[l][j][k] = (w2 @ uw1_bot)[k][j]; b2u[l] = b2 @ uw1_bot ----------------
__global__ void k_small(const float* __restrict__ msg_w2, const float* __restrict__ upd_w1,
                        const float* __restrict__ msg_b2,
                        bf16* __restrict__ W2Ut, float* __restrict__ b2u) {
    __shared__ float row[HID];
    const int l = blockIdx.y;
    const int k = blockIdx.x, j = threadIdx.x;
    const float* w2  = msg_w2 + (size_t)l * HID * HID;
    const float* uw1 = upd_w1 + (size_t)l * 2 * HID * HID;
    const float* b2  = msg_b2 + (size_t)l * HID;
    const float* src = (k < HID) ? &w2[(size_t)k * HID] : b2;
    row[j] = src[j];
    __syncthreads();
    float acc = 0.f;
    #pragma unroll 8
    for (int m = 0; m < HID; ++m)
        acc = fmaf(row[m], uw1[(size_t)(HID + m) * HID + j], acc);
    if (k < HID) W2Ut[(size_t)l * HID * HID + (size_t)j * HID + k] = (bf16)acc;
    else b2u[l * HID + j] = acc;
}

// ---------------- [P|Q] = h16 @ W1t^T (MFMA, no LDS); Q gets +b1 ----------------
__launch_bounds__(256, 4)
__global__ void k_node_pre(const bf16* __restrict__ h16, const bf16* __restrict__ W1t,
                           const float* __restrict__ b1,
                           bf16* __restrict__ P, bf16* __restrict__ Q) {
    const int tid = threadIdx.x;
    const int n0 = blockIdx.x * 64;
    const int lane = tid & 63, wave = tid >> 6;
    const int lr = lane & 15, kq = (lane >> 4) * 8;
    const int bcol = wave * 64;

    const f32x4 z4 = {0.f, 0.f, 0.f, 0.f};
    f32x4 acc[4][4];
    #pragma unroll
    for (int mi = 0; mi < 4; ++mi)
        #pragma unroll
        for (int ni = 0; ni < 4; ++ni) acc[mi][ni] = z4;

    #pragma unroll
    for (int ks = 0; ks < 4; ++ks) {
        bf16x8 av[4], bv[4];
        #pragma unroll
        for (int mi = 0; mi < 4; ++mi)
            av[mi] = *(const bf16x8*)&h16[(size_t)(n0 + mi * 16 + lr) * HID + ks * 32 + kq];
        #pragma unroll
        for (int ni = 0; ni < 4; ++ni)
            bv[ni] = *(const bf16x8*)&W1t[(size_t)(bcol + ni * 16 + lr) * HID + ks * 32 + kq];
        #pragma unroll
        for (int mi = 0; mi < 4; ++mi)
            #pragma unroll
            for (int ni = 0; ni < 4; ++ni)
                acc[mi][ni] = __builtin_amdgcn_mfma_f32_16x16x32_bf16(av[mi], bv[ni],
                                                                      acc[mi][ni], 0, 0, 0);
    }

    bf16* outp = (bcol < 128) ? P : Q;
    const int cb = bcol & 127;
    const int rq = (lane >> 4) * 4;
    #pragma unroll
    for (int ni = 0; ni < 4; ++ni) {
        const int c = cb + ni * 16 + lr;
        const float bias = (bcol >= 128) ? b1[c] : 0.f;
        #pragma unroll
        for (int mi = 0; mi < 4; ++mi) {
            #pragma unroll
            for (int r = 0; r < 4; ++r) {
                const int gr = n0 + mi * 16 + rq + r;
                if (gr < N_NODES) outp[(size_t)gr * HID + c] = (bf16)(acc[mi][ni][r] + bias);
            }
        }
    }
}

// ---------------- aggH[n] = sum_e relu(P[src_e] + Q[n] + attr_e * w1last)  (bf16 io) -------
__global__ void k_agg(const bf16* __restrict__ P, const bf16* __restrict__ Q,
                      const int* __restrict__ row_ptr, const int* __restrict__ s_src,
                      const float* __restrict__ s_attr, const float* __restrict__ w1last,
                      bf16* __restrict__ aggH) {
    const int n = blockIdx.x * 8 + (threadIdx.x >> 5);
    const int c0 = (threadIdx.x & 31) * 4;
    if (n >= N_NODES) return;
    const bf16x4 qb = *(const bf16x4*)&Q[(size_t)n * HID + c0];
    const float4 wl = *(const float4*)&w1last[c0];
    const float qx = (float)qb[0], qy = (float)qb[1], qz = (float)qb[2], qw = (float)qb[3];
    float ax = 0.f, ay = 0.f, az = 0.f, aw = 0.f;
    const int lo = row_ptr[n], hi = row_ptr[n + 1];
    for (int e = lo; e < hi; ++e) {
        const int s = s_src[e];
        const float a = s_attr[e];
        const bf16x4 pb = *(const bf16x4*)&P[(size_t)s * HID + c0];
        ax += fmaxf(fmaf(a, wl.x, (float)pb[0] + qx), 0.f);
        ay += fmaxf(fmaf(a, wl.y, (float)pb[1] + qy), 0.f);
        az += fmaxf(fmaf(a, wl.z, (float)pb[2] + qz), 0.f);
        aw += fmaxf(fmaf(a, wl.w, (float)pb[3] + qw), 0.f);
    }
    bf16x4 o;
    o[0] = (bf16)ax; o[1] = (bf16)ay; o[2] = (bf16)az; o[3] = (bf16)aw;
    *(bf16x4*)&aggH[(size_t)n * HID + c0] = o;
}

// ------- h16 += relu(h16@U1t^T + aggH@W2Ut^T + ub1 + deg*b2u) @ U2t^T + ub2 (MFMA) -------
__launch_bounds__(256, 4)
__global__ void k_node_upd(bf16* __restrict__ h16, const bf16* __restrict__ aggH,
                           const bf16* __restrict__ U1t, const bf16* __restrict__ W2Ut,
                           const float* __restrict__ ub1, const float* __restrict__ b2u,
                           const float* __restrict__ degf,
                           const bf16* __restrict__ U2t, const float* __restrict__ ub2) {
    __shared__ bf16 sT[64 * 136];   // relu'd intermediate tile, +8 pad
    const int tid = threadIdx.x;
    const int n0 = blockIdx.x * 64;
    const int lane = tid & 63, wave = tid >> 6;
    const int lr = lane & 15, kq = (lane >> 4) * 8;
    const int rq = (lane >> 4) * 4;
    const int nw = wave * 32;

    const f32x4 z4 = {0.f, 0.f, 0.f, 0.f};
    f32x4 acc[4][2];
    #pragma unroll
    for (int mi = 0; mi < 4; ++mi) { acc[mi][0] = z4; acc[mi][1] = z4; }

    // GEMM1a: h16 @ U1t^T
    #pragma unroll
    for (int ks = 0; ks < 4; ++ks) {
        bf16x8 av[4], bv[2];
        #pragma unroll
        for (int mi = 0; mi < 4; ++mi)
            av[mi] = *(const bf16x8*)&h16[(size_t)(n0 + mi * 16 + lr) * HID + ks * 32 + kq];
        #pragma unroll
        for (int ni = 0; ni < 2; ++ni)
            bv[ni] = *(const bf16x8*)&U1t[(size_t)(nw + ni * 16 + lr) * HID + ks * 32 + kq];
        #pragma unroll
        for (int mi = 0; mi < 4; ++mi)
            #pragma unroll
            for (int ni = 0; ni < 2; ++ni)
                acc[mi][ni] = __builtin_amdgcn_mfma_f32_16x16x32_bf16(av[mi], bv[ni],
                                                                      acc[mi][ni], 0, 0, 0);
    }
    // GEMM1b: aggH @ W2Ut^T
    #pragma unroll
    for (int ks = 0; ks < 4; ++ks) {
        bf16x8 av[4], bv[2];
        #pragma unroll
        for (int mi = 0; mi < 4; ++mi)
            av[mi] = *(const bf16x8*)&aggH[(size_t)(n0 + mi * 16 + lr) * HID + ks * 32 + kq];
        #pragma unroll
        for (int ni = 0; ni < 2; ++ni)
            bv[ni] = *(const bf16x8*)&W2Ut[(size_t)(nw + ni * 16 + lr) * HID + ks * 32 + kq];
        #pragma unroll
        for (int mi = 0; mi < 4; ++mi)
            #pragma unroll
            for (int ni = 0; ni < 2; ++ni)
                acc[mi][ni] = __builtin_amdgcn_mfma_f32_16x16x32_bf16(av[mi], bv[ni],
                                                                      acc[mi][ni], 0, 0, 0);
    }

    // bias + deg*b2u + relu -> sT (bf16)
    #pragma unroll
    for (int ni = 0; ni < 2; ++ni) {
        const int c = nw + ni * 16 + lr;
        const float bb1 = ub1[c], bb2 = b2u[c];
        #pragma unroll
        for (int mi = 0; mi < 4; ++mi) {
            #pragma unroll
            for (int r = 0; r < 4; ++r) {
                const int row = mi * 16 + rq + r;
                const float dg = degf[n0 + row];
                float v = acc[mi][ni][r] + bb1 + dg * bb2;
                sT[row * 136 + c] = (bf16)fmaxf(v, 0.f);
            }
        }
    }
    __syncthreads();   // also protects h16 epilogue writes vs GEMM1a reads

    // GEMM2: sT @ U2t^T
    f32x4 acc2[4][2];
    #pragma unroll
    for (int mi = 0; mi < 4; ++mi) { acc2[mi][0] = z4; acc2[mi][1] = z4; }
    #pragma unroll
    for (int ks = 0; ks < 4; ++ks) {
        bf16x8 av[4], bv[2];
        #pragma unroll
        for (int mi = 0; mi < 4; ++mi)
            av[mi] = *(const bf16x8*)&sT[(mi * 16 + lr) * 136 + ks * 32 + kq];
        #pragma unroll
        for (int ni = 0; ni < 2; ++ni)
            bv[ni] = *(const bf16x8*)&U2t[(size_t)(nw + ni * 16 + lr) * HID + ks * 32 + kq];
        #pragma unroll
        for (int mi = 0; mi < 4; ++mi)
            #pragma unroll
            for (int ni = 0; ni < 2; ++ni)
                acc2[mi][ni] = __builtin_amdgcn_mfma_f32_16x16x32_bf16(av[mi], bv[ni],
                                                                       acc2[mi][ni], 0, 0, 0);
    }

    #pragma unroll
    for (int ni = 0; ni < 2; ++ni) {
        const int c = nw + ni * 16 + lr;
        const float bb = ub2[c];
        #pragma unroll
        for (int mi = 0; mi < 4; ++mi) {
            #pragma unroll
            for (int r = 0; r < 4; ++r) {
                const int gr = n0 + mi * 16 + rq + r;
                if (gr < N_NODES) {
                    const size_t off = (size_t)gr * HID + c;
                    h16[off] = (bf16)((float)h16[off] + acc2[mi][ni][r] + bb);
                }
            }
        }
    }
}

// ---------------- pooling: contiguous 64-row tiles, run-flush per graph segment -------------
__global__ void k_pool(const bf16* __restrict__ h16, const int* __restrict__ batch,
                       float* __restrict__ pooled) {
    const int n0 = blockIdx.x * 64;
    const int c = threadIdx.x & 127;
    const int half = threadIdx.x >> 7;
    int cur = -1;
    float s = 0.f;
    const int rbeg = n0 + half * 32;
    const int rend = min(rbeg + 32, N_NODES);
    for (int n = rbeg; n < rend; ++n) {
        const int g = batch[n];                      // wave-uniform
        const float v = (float)h16[(size_t)n * HID + c];
        if (g != cur) {
            if (cur >= 0) atomicAdd(&pooled[cur * HID + c], s);
            cur = g; s = v;
        } else {
            s += v;
        }
    }
    if (cur >= 0) atomicAdd(&pooled[cur * HID + c], s);
}

// ---------------- head MLP (fp32); counts from binary search on sorted batch ----------------
__device__ inline int lb(const int* a, int n, int v) {
    int lo = 0, hi = n;
    while (lo < hi) { int m = (lo + hi) >> 1; if (a[m] < v) lo = m + 1; else hi = m; }
    return lo;
}

__global__ void k_head(const float* __restrict__ pooled, const int* __restrict__ batch,
                       const float* __restrict__ hw1, const float* __restrict__ hb1,
                       const float* __restrict__ hw2, const float* __restrict__ hb2,
                       float* __restrict__ out) {
    const int g = blockIdx.x;
    const int c = threadIdx.x;
    __shared__ float sp[HID];
    __shared__ float red[HID];
    __shared__ int sb[2];
    if (c == 0) { sb[0] = lb(batch, N_NODES, g); sb[1] = lb(batch, N_NODES, g + 1); }
    __syncthreads();
    const float cnt = fmaxf((float)(sb[1] - sb[0]), 1.f);
    sp[c] = pooled[g * HID + c] / cnt;
    __syncthreads();
    float acc = hb1[c];
    #pragma unroll 8
    for (int k = 0; k < HID; ++k) acc = fmaf(sp[k], hw1[k * HID + c], acc);
    red[c] = fmaxf(acc, 0.f) * hw2[c];
    __syncthreads();
    for (int s = 64; s > 0; s >>= 1) {
        if (c < s) red[c] += red[c + s];
        __syncthreads();
    }
    if (c == 0) out[g] = red[0] + hb2[0];
}

extern "C" void kernel_launch(void* const* d_in, const int* in_sizes, int n_in,
                              void* d_out, int out_size, void* d_ws, size_t ws_size,
                              hipStream_t stream) {
    const int*   z       = (const int*)d_in[0];
    const int*   ei      = (const int*)d_in[1];
    const float* eattr   = (const float*)d_in[2];
    const int*   batch   = (const int*)d_in[3];
    const float* embed   = (const float*)d_in[4];
    const float* msg_w1  = (const float*)d_in[5];
    const float* msg_b1  = (const float*)d_in[6];
    const float* msg_w2  = (const float*)d_in[7];
    const float* msg_b2  = (const float*)d_in[8];
    const float* upd_w1  = (const float*)d_in[9];
    const float* upd_b1  = (const float*)d_in[10];
    const float* upd_w2  = (const float*)d_in[11];
    const float* upd_b2  = (const float*)d_in[12];
    const float* head_w1 = (const float*)d_in[13];
    const float* head_b1 = (const float*)d_in[14];
    const float* head_w2 = (const float*)d_in[15];
    const float* head_b2 = (const float*)d_in[16];
    float* out = (float*)d_out;

    // workspace layout (~56 MB)
    float* pooled = (float*)d_ws;                       // 64 x 128
    float* b2u    = pooled + NUM_GRAPHS * HID;          // 3 x 128
    float* s_attr = b2u + 3 * HID;                      // E
    float* degf   = s_attr + N_EDGES;                   // NPAD
    int* deg_i    = (int*)(degf + NPAD);
    int* row_ptr  = deg_i + N_NODES;
    int* partial  = row_ptr + N_NODES + 1;
    int* cursor   = partial + 256;
    int* s_src    = cursor + N_NODES;                   // E
    bf16* h16     = (bf16*)((((unsigned long long)(s_src + N_EDGES)) + 15ULL) & ~15ULL);
    bf16* P       = h16 + (size_t)NPAD * HID;
    bf16* Q       = P + (size_t)NPAD * HID;
    bf16* aggH    = Q + (size_t)NPAD * HID;
    bf16* W1t     = aggH + (size_t)NPAD * HID;          // 3 x 256 x 128
    bf16* U1t     = W1t + 3 * 256 * HID;                // 3 x 128 x 128
    bf16* W2Ut    = U1t + 3 * HID * HID;
    bf16* U2t     = W2Ut + 3 * HID * HID;

    const int* esrc = ei;
    const int* edst = ei + N_EDGES;

    k_embed<<<(NPAD * 16 + 255) / 256, 256, 0, stream>>>(z, embed, h16);

    // CSR build + all-layer weight prep
    hipMemsetAsync(deg_i, 0, N_NODES * sizeof(int), stream);
    k_hist<<<(N_EDGES + 255) / 256, 256, 0, stream>>>(edst, deg_i);
    k_scan1<<<SCAN_B, 256, 0, stream>>>(deg_i, partial);
    k_scan2<<<1, 256, 0, stream>>>(partial, row_ptr);
    k_scan3<<<SCAN_B, 256, 0, stream>>>(deg_i, partial, row_ptr, cursor, degf);
    k_scatter<<<(N_EDGES + 255) / 256, 256, 0, stream>>>(esrc, edst, eattr, cursor, s_src, s_attr);
    {
        dim3 g1(512, 3);
        k_wprep<<<g1, 128, 0, stream>>>(msg_w1, upd_w1, upd_w2, W1t, U1t, U2t);
        dim3 g2(HID + 1, 3);
        k_small<<<g2, HID, 0, stream>>>(msg_w2, upd_w1, msg_b2, W2Ut, b2u);
    }

    const int nblk = NPAD / 64;
    for (int l = 0; l < 3; ++l) {
        const float* w1 = msg_w1 + (size_t)l * 257 * HID;
        k_node_pre<<<nblk, 256, 0, stream>>>(h16, W1t + (size_t)l * 256 * HID,
                                             msg_b1 + (size_t)l * HID, P, Q);
        k_agg<<<(N_NODES + 7) / 8, 256, 0, stream>>>(
            P, Q, row_ptr, s_src, s_attr, w1 + 256 * HID, aggH);
        k_node_upd<<<nblk, 256, 0, stream>>>(
            h16, aggH, U1t + (size_t)l * HID * HID, W2Ut + (size_t)l * HID * HID,
            upd_b1 + (size_t)l * HID, b2u + l * HID, degf,
            U2t + (size_t)l * HID * HID, upd_b2 + (size_t)l * HID);
    }
    hipMemsetAsync(pooled, 0, NUM_GRAPHS * HID * sizeof(float), stream);
    k_pool<<<nblk, 256, 0, stream>>>(h16, batch, pooled);
    k_head<<<NUM_GRAPHS, 128, 0, stream>>>(pooled, batch, head_w1, head_b1, head_w2, head_b2, out);
}

// Round 7
// 376.882 us; speedup vs baseline: 13.2444x; 1.0639x over previous
//
#include <hip/hip_runtime.h>

#define N_NODES 50000
#define NPAD 50048          // 782 * 64
#define N_EDGES 400000
#define HID 128
#define NUM_GRAPHS 64
#define SCAN_B 196          // ceil(N_NODES/256)

typedef __bf16 bf16;
typedef bf16 bf16x8 __attribute__((ext_vector_type(8)));
typedef float f32x4 __attribute__((ext_vector_type(4)));

__device__ inline bf16x8 cvt8(const float* p) {
    const float4 a = *(const float4*)p;
    const float4 b = *(const float4*)(p + 4);
    bf16x8 v;
    v[0] = (bf16)a.x; v[1] = (bf16)a.y; v[2] = (bf16)a.z; v[3] = (bf16)a.w;
    v[4] = (bf16)b.x; v[5] = (bf16)b.y; v[6] = (bf16)b.z; v[7] = (bf16)b.w;
    return v;
}

// ---------------- CSR build ----------------
__global__ void k_hist(const int* __restrict__ edst, int* __restrict__ deg) {
    int e = blockIdx.x * 256 + threadIdx.x;
    if (e < N_EDGES) atomicAdd(&deg[edst[e]], 1);
}

__global__ void k_scan1(const int* __restrict__ deg, int* __restrict__ partial) {
    __shared__ int buf[256];
    int i = blockIdx.x * 256 + threadIdx.x;
    buf[threadIdx.x] = (i < N_NODES) ? deg[i] : 0;
    __syncthreads();
    for (int off = 128; off > 0; off >>= 1) {
        if (threadIdx.x < off) buf[threadIdx.x] += buf[threadIdx.x + off];
        __syncthreads();
    }
    if (threadIdx.x == 0) partial[blockIdx.x] = buf[0];
}

__global__ void k_scan2(int* __restrict__ partial, int* __restrict__ row_ptr) {
    __shared__ int buf[256];
    int v = (threadIdx.x < SCAN_B) ? partial[threadIdx.x] : 0;
    buf[threadIdx.x] = v;
    __syncthreads();
    for (int off = 1; off < 256; off <<= 1) {
        int t = (threadIdx.x >= off) ? buf[threadIdx.x - off] : 0;
        __syncthreads();
        buf[threadIdx.x] += t;
        __syncthreads();
    }
    if (threadIdx.x < SCAN_B) partial[threadIdx.x] = buf[threadIdx.x] - v;  // exclusive
    if (threadIdx.x == 255) row_ptr[N_NODES] = buf[255];
}

__global__ void k_scan3(const int* __restrict__ deg, const int* __restrict__ partial,
                        int* __restrict__ row_ptr, int* __restrict__ cursor) {
    __shared__ int buf[256];
    int i = blockIdx.x * 256 + threadIdx.x;
    int v = (i < N_NODES) ? deg[i] : 0;
    buf[threadIdx.x] = v;
    __syncthreads();
    for (int off = 1; off < 256; off <<= 1) {
        int t = (threadIdx.x >= off) ? buf[threadIdx.x - off] : 0;
        __syncthreads();
        buf[threadIdx.x] += t;
        __syncthreads();
    }
    if (i < N_NODES) {
        int ex = partial[blockIdx.x] + buf[threadIdx.x] - v;
        row_ptr[i] = ex;
        cursor[i] = ex;
    }
}

__global__ void k_scatter(const int* __restrict__ esrc, const int* __restrict__ edst,
                          const float* __restrict__ attr, int* __restrict__ cursor,
                          int* __restrict__ s_src, float* __restrict__ s_attr) {
    int e = blockIdx.x * 256 + threadIdx.x;
    if (e >= N_EDGES) return;
    int p = atomicAdd(&cursor[edst[e]], 1);
    s_src[p] = esrc[e];
    s_attr[p] = attr[e];
}

// ---------------- weight prep (all layers upfront): bf16 [n][k] transposes ----------------
__global__ void k_wprep(const float* __restrict__ msg_w1, const float* __restrict__ upd_w1,
                        const float* __restrict__ upd_w2,
                        bf16* __restrict__ W1t, bf16* __restrict__ U1t,
                        bf16* __restrict__ U2t) {
    const int l = blockIdx.y;
    const int n = blockIdx.x, k = threadIdx.x;
    const float* w1  = msg_w1 + (size_t)l * 257 * HID;
    const float* uw1 = upd_w1 + (size_t)l * 2 * HID * HID;
    const float* uw2 = upd_w2 + (size_t)l * HID * HID;
    if (n < 256) {
        W1t[(size_t)l * 256 * HID + n * HID + k] =
            (bf16)w1[(size_t)((n & 128) + k) * HID + (n & 127)];
    } else if (n < 384) {
        const int nn = n - 256;
        U1t[(size_t)l * HID * HID + nn * HID + k] = (bf16)uw1[(size_t)k * HID + nn];
    } else {
        const int nn = n - 384;
        U2t[(size_t)l * HID * HID + nn * HID + k] = (bf16)uw2[(size_t)k * HID + nn];
    }
}

// ---------------- W2Ut[l][j][k] = (w2 @ uw1_bot)[k][j]; b2u[l] = b2 @ uw1_bot ----------------
__global__ void k_small(const float* __restrict__ msg_w2, const float* __restrict__ upd_w1,
                        const float* __restrict__ msg_b2,
                        bf16* __restrict__ W2Ut, float* __restrict__ b2u) {
    __shared__ float row[HID];
    const int l = blockIdx.y;
    const int k = blockIdx.x, j = threadIdx.x;
    const float* w2  = msg_w2 + (size_t)l * HID * HID;
    const float* uw1 = upd_w1 + (size_t)l * 2 * HID * HID;
    const float* b2  = msg_b2 + (size_t)l * HID;
    const float* src = (k < HID) ? &w2[(size_t)k * HID] : b2;
    row[j] = src[j];
    __syncthreads();
    float acc = 0.f;
    #pragma unroll 8
    for (int m = 0; m < HID; ++m)
        acc = fmaf(row[m], uw1[(size_t)(HID + m) * HID + j], acc);
    if (k < HID) W2Ut[(size_t)l * HID * HID + (size_t)j * HID + k] = (bf16)acc;
    else b2u[l * HID + j] = acc;
}

// ---------------- fused embed + layer-0 pre: h16 = bf16(embed[z]); [P|Q] = h @ W1t^T -------
__launch_bounds__(256, 4)
__global__ void k_embed_pre(const int* __restrict__ z, const float* __restrict__ embed,
                            const bf16* __restrict__ W1t, const float* __restrict__ b1,
                            bf16* __restrict__ h16, bf16* __restrict__ P, bf16* __restrict__ Q) {
    __shared__ bf16 sH[64 * 136];
    const int tid = threadIdx.x;
    const int n0 = blockIdx.x * 64;
    {
        const int r = tid & 63, cg = tid >> 6;
        const int n = n0 + r;
        const bool valid = n < N_NODES;
        const float* src = valid ? &embed[(size_t)z[n] * HID + cg * 32] : embed;
        #pragma unroll
        for (int i = 0; i < 4; ++i) {
            bf16x8 v;
            if (valid) {
                v = cvt8(src + i * 8);
            } else {
                for (int j = 0; j < 8; ++j) v[j] = (bf16)0.f;
            }
            *(bf16x8*)&sH[r * 136 + cg * 32 + i * 8] = v;
            *(bf16x8*)&h16[(size_t)n * HID + cg * 32 + i * 8] = v;
        }
    }
    __syncthreads();
    const int lane = tid & 63, wave = tid >> 6;
    const int lr = lane & 15, kq = (lane >> 4) * 8, rq = (lane >> 4) * 4;
    const int bcol = wave * 64;

    const f32x4 z4 = {0.f, 0.f, 0.f, 0.f};
    f32x4 acc[4][4];
    #pragma unroll
    for (int mi = 0; mi < 4; ++mi)
        #pragma unroll
        for (int ni = 0; ni < 4; ++ni) acc[mi][ni] = z4;

    #pragma unroll
    for (int ks = 0; ks < 4; ++ks) {
        bf16x8 av[4], bv[4];
        #pragma unroll
        for (int mi = 0; mi < 4; ++mi)
            av[mi] = *(const bf16x8*)&sH[(mi * 16 + lr) * 136 + ks * 32 + kq];
        #pragma unroll
        for (int ni = 0; ni < 4; ++ni)
            bv[ni] = *(const bf16x8*)&W1t[(size_t)(bcol + ni * 16 + lr) * HID + ks * 32 + kq];
        #pragma unroll
        for (int mi = 0; mi < 4; ++mi)
            #pragma unroll
            for (int ni = 0; ni < 4; ++ni)
                acc[mi][ni] = __builtin_amdgcn_mfma_f32_16x16x32_bf16(av[mi], bv[ni],
                                                                      acc[mi][ni], 0, 0, 0);
    }
    bf16* outp = (bcol < 128) ? P : Q;
    const int cb = bcol & 127;
    #pragma unroll
    for (int ni = 0; ni < 4; ++ni) {
        const int c = cb + ni * 16 + lr;
        const float bias = (bcol >= 128) ? b1[c] : 0.f;
        #pragma unroll
        for (int mi = 0; mi < 4; ++mi)
            #pragma unroll
            for (int r = 0; r < 4; ++r) {
                const int gr = n0 + mi * 16 + rq + r;
                if (gr < N_NODES) outp[(size_t)gr * HID + c] = (bf16)(acc[mi][ni][r] + bias);
            }
    }
}

// ---------------- fused layer: agg(LDS) -> upd GEMMs -> h16 += ... -> [next-layer pre] -------
template<int DO_PRE>
__launch_bounds__(256, 3)
__global__ void k_layer(bf16* __restrict__ h16,
                        const bf16* __restrict__ P, const bf16* __restrict__ Q,
                        const int* __restrict__ row_ptr, const int* __restrict__ s_src,
                        const float* __restrict__ s_attr, const float* __restrict__ w1last,
                        const bf16* __restrict__ U1t, const bf16* __restrict__ W2Ut,
                        const float* __restrict__ ub1, const float* __restrict__ b2u,
                        const bf16* __restrict__ U2t, const float* __restrict__ ub2,
                        const bf16* __restrict__ W1tn, const float* __restrict__ b1n,
                        bf16* __restrict__ Pn, bf16* __restrict__ Qn) {
    __shared__ bf16 sAgg[64 * 136];   // agg tile; reused as new-h tile for phase C
    __shared__ bf16 sT[64 * 136];     // relu'd intermediate tile
    __shared__ float sDeg[64];
    const int tid = threadIdx.x;
    const int n0 = blockIdx.x * 64;

    // ---- Phase A: aggregate incoming messages into sAgg ----
    {
        const int grp = tid >> 4, ln = tid & 15, c8 = ln * 8;
        float wl[8];
        #pragma unroll
        for (int j = 0; j < 8; ++j) wl[j] = w1last[c8 + j];
        #pragma unroll
        for (int t = 0; t < 4; ++t) {
            const int row = t * 16 + grp;
            const int n = n0 + row;
            float a8[8];
            #pragma unroll
            for (int j = 0; j < 8; ++j) a8[j] = 0.f;
            if (n < N_NODES) {
                const int lo = row_ptr[n], hi = row_ptr[n + 1];
                if (ln == 0) sDeg[row] = (float)(hi - lo);
                const bf16x8 qv = *(const bf16x8*)&Q[(size_t)n * HID + c8];
                float q8[8];
                #pragma unroll
                for (int j = 0; j < 8; ++j) q8[j] = (float)qv[j];
                int e = lo;
                for (; e + 2 <= hi; e += 2) {
                    const int s0 = s_src[e], s1 = s_src[e + 1];
                    const float t0 = s_attr[e], t1 = s_attr[e + 1];
                    const bf16x8 p0 = *(const bf16x8*)&P[(size_t)s0 * HID + c8];
                    const bf16x8 p1 = *(const bf16x8*)&P[(size_t)s1 * HID + c8];
                    #pragma unroll
                    for (int j = 0; j < 8; ++j) {
                        a8[j] += fmaxf(fmaf(t0, wl[j], q8[j] + (float)p0[j]), 0.f);
                        a8[j] += fmaxf(fmaf(t1, wl[j], q8[j] + (float)p1[j]), 0.f);
                    }
                }
                if (e < hi) {
                    const int s0 = s_src[e];
                    const float t0 = s_attr[e];
                    const bf16x8 p0 = *(const bf16x8*)&P[(size_t)s0 * HID + c8];
                    #pragma unroll
                    for (int j = 0; j < 8; ++j)
                        a8[j] += fmaxf(fmaf(t0, wl[j], q8[j] + (float)p0[j]), 0.f);
                }
            } else if (ln == 0) {
                sDeg[row] = 0.f;
            }
            bf16x8 o;
            #pragma unroll
            for (int j = 0; j < 8; ++j) o[j] = (bf16)a8[j];
            *(bf16x8*)&sAgg[row * 136 + c8] = o;
        }
    }
    __syncthreads();

    // ---- Phase B: acc = h16 @ U1t^T + agg @ W2Ut^T ----
    const int lane = tid & 63, wave = tid >> 6;
    const int lr = lane & 15, kq = (lane >> 4) * 8, rq = (lane >> 4) * 4;
    const int nw = wave * 32;
    const f32x4 z4 = {0.f, 0.f, 0.f, 0.f};

    f32x4 acc[4][2];
    #pragma unroll
    for (int mi = 0; mi < 4; ++mi) { acc[mi][0] = z4; acc[mi][1] = z4; }

    #pragma unroll
    for (int ks = 0; ks < 4; ++ks) {
        bf16x8 av[4], bv[2];
        #pragma unroll
        for (int mi = 0; mi < 4; ++mi)
            av[mi] = *(const bf16x8*)&h16[(size_t)(n0 + mi * 16 + lr) * HID + ks * 32 + kq];
        #pragma unroll
        for (int ni = 0; ni < 2; ++ni)
            bv[ni] = *(const bf16x8*)&U1t[(size_t)(nw + ni * 16 + lr) * HID + ks * 32 + kq];
        #pragma unroll
        for (int mi = 0; mi < 4; ++mi)
            #pragma unroll
            for (int ni = 0; ni < 2; ++ni)
                acc[mi][ni] = __builtin_amdgcn_mfma_f32_16x16x32_bf16(av[mi], bv[ni],
                                                                      acc[mi][ni], 0, 0, 0);
    }
    #pragma unroll
    for (int ks = 0; ks < 4; ++ks) {
        bf16x8 av[4], bv[2];
        #pragma unroll
        for (int mi = 0; mi < 4; ++mi)
            av[mi] = *(const bf16x8*)&sAgg[(mi * 16 + lr) * 136 + ks * 32 + kq];
        #pragma unroll
        for (int ni = 0; ni < 2; ++ni)
            bv[ni] = *(const bf16x8*)&W2Ut[(size_t)(nw + ni * 16 + lr) * HID + ks * 32 + kq];
        #pragma unroll
        for (int mi = 0; mi < 4; ++mi)
            #pragma unroll
            for (int ni = 0; ni < 2; ++ni)
                acc[mi][ni] = __builtin_amdgcn_mfma_f32_16x16x32_bf16(av[mi], bv[ni],
                                                                      acc[mi][ni], 0, 0, 0);
    }

    // bias + deg*b2u + relu -> sT
    #pragma unroll
    for (int ni = 0; ni < 2; ++ni) {
        const int c = nw + ni * 16 + lr;
        const float bb1 = ub1[c], bb2 = b2u[c];
        #pragma unroll
        for (int mi = 0; mi < 4; ++mi)
            #pragma unroll
            for (int r = 0; r < 4; ++r) {
                const int row = mi * 16 + rq + r;
                float v = acc[mi][ni][r] + bb1 + sDeg[row] * bb2;
                sT[row * 136 + c] = (bf16)fmaxf(v, 0.f);
            }
    }
    __syncthreads();   // sT ready; all sAgg reads done

    // GEMM2: sT @ U2t^T
    f32x4 acc2[4][2];
    #pragma unroll
    for (int mi = 0; mi < 4; ++mi) { acc2[mi][0] = z4; acc2[mi][1] = z4; }
    #pragma unroll
    for (int ks = 0; ks < 4; ++ks) {
        bf16x8 av[4], bv[2];
        #pragma unroll
        for (int mi = 0; mi < 4; ++mi)
            av[mi] = *(const bf16x8*)&sT[(mi * 16 + lr) * 136 + ks * 32 + kq];
        #pragma unroll
        for (int ni = 0; ni < 2; ++ni)
            bv[ni] = *(const bf16x8*)&U2t[(size_t)(nw + ni * 16 + lr) * HID + ks * 32 + kq];
        #pragma unroll
        for (int mi = 0; mi < 4; ++mi)
            #pragma unroll
            for (int ni = 0; ni < 2; ++ni)
                acc2[mi][ni] = __builtin_amdgcn_mfma_f32_16x16x32_bf16(av[mi], bv[ni],
                                                                       acc2[mi][ni], 0, 0, 0);
    }

    // epilogue: newh = h16 + acc2 + ub2 -> global h16 and sAgg (as next-layer A tile)
    #pragma unroll
    for (int ni = 0; ni < 2; ++ni) {
        const int c = nw + ni * 16 + lr;
        const float bb = ub2[c];
        #pragma unroll
        for (int mi = 0; mi < 4; ++mi)
            #pragma unroll
            for (int r = 0; r < 4; ++r) {
                const int row = mi * 16 + rq + r;
                const int gr = n0 + row;
                float nh = 0.f;
                if (gr < N_NODES) {
                    const size_t off = (size_t)gr * HID + c;
                    nh = (float)h16[off] + acc2[mi][ni][r] + bb;
                    h16[off] = (bf16)nh;
                }
                if (DO_PRE) sAgg[row * 136 + c] = (bf16)nh;
            }
    }

    if (DO_PRE) {
        __syncthreads();
        // ---- Phase C: next-layer [P|Q] = newh @ W1tn^T ----
        const int bcol = wave * 64;
        f32x4 pacc[4][4];
        #pragma unroll
        for (int mi = 0; mi < 4; ++mi)
            #pragma unroll
            for (int ni = 0; ni < 4; ++ni) pacc[mi][ni] = z4;

        #pragma unroll
        for (int ks = 0; ks < 4; ++ks) {
            bf16x8 av[4], bv[4];
            #pragma unroll
            for (int mi = 0; mi < 4; ++mi)
                av[mi] = *(const bf16x8*)&sAgg[(mi * 16 + lr) * 136 + ks * 32 + kq];
            #pragma unroll
            for (int ni = 0; ni < 4; ++ni)
                bv[ni] = *(const bf16x8*)&W1tn[(size_t)(bcol + ni * 16 + lr) * HID + ks * 32 + kq];
            #pragma unroll
            for (int mi = 0; mi < 4; ++mi)
                #pragma unroll
                for (int ni = 0; ni < 4; ++ni)
                    pacc[mi][ni] = __builtin_amdgcn_mfma_f32_16x16x32_bf16(av[mi], bv[ni],
                                                                           pacc[mi][ni], 0, 0, 0);
        }
        bf16* outp = (bcol < 128) ? Pn : Qn;
        const int cb = bcol & 127;
        #pragma unroll
        for (int ni = 0; ni < 4; ++ni) {
            const int c = cb + ni * 16 + lr;
            const float bias = (bcol >= 128) ? b1n[c] : 0.f;
            #pragma unroll
            for (int mi = 0; mi < 4; ++mi)
                #pragma unroll
                for (int r = 0; r < 4; ++r) {
                    const int gr = n0 + mi * 16 + rq + r;
                    if (gr < N_NODES) outp[(size_t)gr * HID + c] = (bf16)(pacc[mi][ni][r] + bias);
                }
        }
    }
}

// ---------------- pooling: contiguous 64-row tiles, run-flush per graph segment -------------
__global__ void k_pool(const bf16* __restrict__ h16, const int* __restrict__ batch,
                       float* __restrict__ pooled) {
    const int n0 = blockIdx.x * 64;
    const int c = threadIdx.x & 127;
    const int half = threadIdx.x >> 7;
    int cur = -1;
    float s = 0.f;
    const int rbeg = n0 + half * 32;
    const int rend = min(rbeg + 32, N_NODES);
    for (int n = rbeg; n < rend; ++n) {
        const int g = batch[n];
        const float v = (float)h16[(size_t)n * HID + c];
        if (g != cur) {
            if (cur >= 0) atomicAdd(&pooled[cur * HID + c], s);
            cur = g; s = v;
        } else {
            s += v;
        }
    }
    if (cur >= 0) atomicAdd(&pooled[cur * HID + c], s);
}

// ---------------- head MLP (fp32); counts via binary search on sorted batch ----------------
__device__ inline int lb(const int* a, int n, int v) {
    int lo = 0, hi = n;
    while (lo < hi) { int m = (lo + hi) >> 1; if (a[m] < v) lo = m + 1; else hi = m; }
    return lo;
}

__global__ void k_head(const float* __restrict__ pooled, const int* __restrict__ batch,
                       const float* __restrict__ hw1, const float* __restrict__ hb1,
                       const float* __restrict__ hw2, const float* __restrict__ hb2,
                       float* __restrict__ out) {
    const int g = blockIdx.x;
    const int c = threadIdx.x;
    __shared__ float sp[HID];
    __shared__ float red[HID];
    __shared__ int sb[2];
    if (c == 0) { sb[0] = lb(batch, N_NODES, g); sb[1] = lb(batch, N_NODES, g + 1); }
    __syncthreads();
    const float cnt = fmaxf((float)(sb[1] - sb[0]), 1.f);
    sp[c] = pooled[g * HID + c] / cnt;
    __syncthreads();
    float acc = hb1[c];
    #pragma unroll 8
    for (int k = 0; k < HID; ++k) acc = fmaf(sp[k], hw1[k * HID + c], acc);
    red[c] = fmaxf(acc, 0.f) * hw2[c];
    __syncthreads();
    for (int s = 64; s > 0; s >>= 1) {
        if (c < s) red[c] += red[c + s];
        __syncthreads();
    }
    if (c == 0) out[g] = red[0] + hb2[0];
}

extern "C" void kernel_launch(void* const* d_in, const int* in_sizes, int n_in,
                              void* d_out, int out_size, void* d_ws, size_t ws_size,
                              hipStream_t stream) {
    const int*   z       = (const int*)d_in[0];
    const int*   ei      = (const int*)d_in[1];
    const float* eattr   = (const float*)d_in[2];
    const int*   batch   = (const int*)d_in[3];
    const float* embed   = (const float*)d_in[4];
    const float* msg_w1  = (const float*)d_in[5];
    const float* msg_b1  = (const float*)d_in[6];
    const float* msg_w2  = (const float*)d_in[7];
    const float* msg_b2  = (const float*)d_in[8];
    const float* upd_w1  = (const float*)d_in[9];
    const float* upd_b1  = (const float*)d_in[10];
    const float* upd_w2  = (const float*)d_in[11];
    const float* upd_b2  = (const float*)d_in[12];
    const float* head_w1 = (const float*)d_in[13];
    const float* head_b1 = (const float*)d_in[14];
    const float* head_w2 = (const float*)d_in[15];
    const float* head_b2 = (const float*)d_in[16];
    float* out = (float*)d_out;

    // workspace layout (~68 MB)
    float* pooled = (float*)d_ws;                       // 64 x 128
    float* b2u    = pooled + NUM_GRAPHS * HID;          // 3 x 128
    float* s_attr = b2u + 3 * HID;                      // E
    int* deg_i    = (int*)(s_attr + N_EDGES);
    int* row_ptr  = deg_i + N_NODES;                    // N+1
    int* partial  = row_ptr + N_NODES + 1;              // 256
    int* cursor   = partial + 256;                      // N
    int* s_src    = cursor + N_NODES;                   // E
    bf16* h16     = (bf16*)((((unsigned long long)(s_src + N_EDGES)) + 15ULL) & ~15ULL);
    bf16* P0      = h16 + (size_t)NPAD * HID;
    bf16* Q0      = P0 + (size_t)NPAD * HID;
    bf16* P1      = Q0 + (size_t)NPAD * HID;
    bf16* Q1      = P1 + (size_t)NPAD * HID;
    bf16* W1t     = Q1 + (size_t)NPAD * HID;            // 3 x 256 x 128
    bf16* U1t     = W1t + 3 * 256 * HID;                // 3 x 128 x 128
    bf16* W2Ut    = U1t + 3 * HID * HID;
    bf16* U2t     = W2Ut + 3 * HID * HID;

    const int* esrc = ei;
    const int* edst = ei + N_EDGES;

    // CSR build + all-layer weight prep
    hipMemsetAsync(deg_i, 0, N_NODES * sizeof(int), stream);
    k_hist<<<(N_EDGES + 255) / 256, 256, 0, stream>>>(edst, deg_i);
    k_scan1<<<SCAN_B, 256, 0, stream>>>(deg_i, partial);
    k_scan2<<<1, 256, 0, stream>>>(partial, row_ptr);
    k_scan3<<<SCAN_B, 256, 0, stream>>>(deg_i, partial, row_ptr, cursor);
    k_scatter<<<(N_EDGES + 255) / 256, 256, 0, stream>>>(esrc, edst, eattr, cursor, s_src, s_attr);
    {
        dim3 g1(512, 3);
        k_wprep<<<g1, 128, 0, stream>>>(msg_w1, upd_w1, upd_w2, W1t, U1t, U2t);
        dim3 g2(HID + 1, 3);
        k_small<<<g2, HID, 0, stream>>>(msg_w2, upd_w1, msg_b2, W2Ut, b2u);
    }

    const int nblk = NPAD / 64;
    // embed + layer-0 pre
    k_embed_pre<<<nblk, 256, 0, stream>>>(z, embed, W1t, msg_b1, h16, P0, Q0);

    bf16* Pa = P0; bf16* Qa = Q0; bf16* Pb = P1; bf16* Qb = Q1;
    for (int l = 0; l < 3; ++l) {
        const float* w1last = msg_w1 + (size_t)l * 257 * HID + 256 * HID;
        const bf16* U1l  = U1t  + (size_t)l * HID * HID;
        const bf16* W2Ul = W2Ut + (size_t)l * HID * HID;
        const bf16* U2l  = U2t  + (size_t)l * HID * HID;
        if (l < 2) {
            k_layer<1><<<nblk, 256, 0, stream>>>(
                h16, Pa, Qa, row_ptr, s_src, s_attr, w1last,
                U1l, W2Ul, upd_b1 + (size_t)l * HID, b2u + l * HID,
                U2l, upd_b2 + (size_t)l * HID,
                W1t + (size_t)(l + 1) * 256 * HID, msg_b1 + (size_t)(l + 1) * HID, Pb, Qb);
            bf16* tp = Pa; Pa = Pb; Pb = tp;
            bf16* tq = Qa; Qa = Qb; Qb = tq;
        } else {
            k_layer<0><<<nblk, 256, 0, stream>>>(
                h16, Pa, Qa, row_ptr, s_src, s_attr, w1last,
                U1l, W2Ul, upd_b1 + (size_t)l * HID, b2u + l * HID,
                U2l, upd_b2 + (size_t)l * HID,
                nullptr, nullptr, nullptr, nullptr);
        }
    }
    hipMemsetAsync(pooled, 0, NUM_GRAPHS * HID * sizeof(float), stream);
    k_pool<<<nblk, 256, 0, stream>>>(h16, batch, pooled);
    k_head<<<NUM_GRAPHS, 128, 0, stream>>>(pooled, batch, head_w1, head_b1, head_w2, head_b2, out);
}

// Round 8
// 315.906 us; speedup vs baseline: 15.8008x; 1.1930x over previous
//
#include <hip/hip_runtime.h>

#define N_NODES 50000
#define NPAD 50048          // 782 * 64
#define N_EDGES 400000
#define HID 128
#define NUM_GRAPHS 64
#define SCAN_B 196          // ceil(N_NODES/256)

typedef __bf16 bf16;
typedef bf16 bf16x8 __attribute__((ext_vector_type(8)));
typedef float f32x4 __attribute__((ext_vector_type(4)));

__device__ inline bf16x8 cvt8(const float* p) {
    const float4 a = *(const float4*)p;
    const float4 b = *(const float4*)(p + 4);
    bf16x8 v;
    v[0] = (bf16)a.x; v[1] = (bf16)a.y; v[2] = (bf16)a.z; v[3] = (bf16)a.w;
    v[4] = (bf16)b.x; v[5] = (bf16)b.y; v[6] = (bf16)b.z; v[7] = (bf16)b.w;
    return v;
}

// coalesced 64x128 bf16 tile copy: LDS(ld=136) -> global rows n0..n0+63
__device__ __forceinline__ void tile_out(const bf16* lds, bf16* g, int n0, int tid) {
    #pragma unroll
    for (int u = 0; u < 4; ++u) {
        const int unit = u * 256 + tid;          // 0..1023
        const int row = unit >> 4;
        const int ci = (unit & 15) * 8;
        *(bf16x8*)&g[(size_t)(n0 + row) * HID + ci] =
            *(const bf16x8*)&lds[row * 136 + ci];
    }
}

// ---------------- CSR build ----------------
__global__ void k_hist(const int* __restrict__ edst, int* __restrict__ deg) {
    int e = blockIdx.x * 256 + threadIdx.x;
    if (e < N_EDGES) atomicAdd(&deg[edst[e]], 1);
}

__global__ void k_scan1(const int* __restrict__ deg, int* __restrict__ partial) {
    __shared__ int buf[256];
    int i = blockIdx.x * 256 + threadIdx.x;
    buf[threadIdx.x] = (i < N_NODES) ? deg[i] : 0;
    __syncthreads();
    for (int off = 128; off > 0; off >>= 1) {
        if (threadIdx.x < off) buf[threadIdx.x] += buf[threadIdx.x + off];
        __syncthreads();
    }
    if (threadIdx.x == 0) partial[blockIdx.x] = buf[0];
}

__global__ void k_scan2(int* __restrict__ partial, int* __restrict__ row_ptr) {
    __shared__ int buf[256];
    int v = (threadIdx.x < SCAN_B) ? partial[threadIdx.x] : 0;
    buf[threadIdx.x] = v;
    __syncthreads();
    for (int off = 1; off < 256; off <<= 1) {
        int t = (threadIdx.x >= off) ? buf[threadIdx.x - off] : 0;
        __syncthreads();
        buf[threadIdx.x] += t;
        __syncthreads();
    }
    if (threadIdx.x < SCAN_B) partial[threadIdx.x] = buf[threadIdx.x] - v;  // exclusive
    if (threadIdx.x == 255) row_ptr[N_NODES] = buf[255];
}

__global__ void k_scan3(const int* __restrict__ deg, const int* __restrict__ partial,
                        int* __restrict__ row_ptr, int* __restrict__ cursor) {
    __shared__ int buf[256];
    int i = blockIdx.x * 256 + threadIdx.x;
    int v = (i < N_NODES) ? deg[i] : 0;
    buf[threadIdx.x] = v;
    __syncthreads();
    for (int off = 1; off < 256; off <<= 1) {
        int t = (threadIdx.x >= off) ? buf[threadIdx.x - off] : 0;
        __syncthreads();
        buf[threadIdx.x] += t;
        __syncthreads();
    }
    if (i < N_NODES) {
        int ex = partial[blockIdx.x] + buf[threadIdx.x] - v;
        row_ptr[i] = ex;
        cursor[i] = ex;
    }
}

__global__ void k_scatter(const int* __restrict__ esrc, const int* __restrict__ edst,
                          const float* __restrict__ attr, int* __restrict__ cursor,
                          int* __restrict__ s_src, float* __restrict__ s_attr) {
    int e = blockIdx.x * 256 + threadIdx.x;
    if (e >= N_EDGES) return;
    int p = atomicAdd(&cursor[edst[e]], 1);
    s_src[p] = esrc[e];
    s_attr[p] = attr[e];
}

// ---------------- weight prep (all layers upfront): bf16 [n][k] transposes ----------------
__global__ void k_wprep(const float* __restrict__ msg_w1, const float* __restrict__ upd_w1,
                        const float* __restrict__ upd_w2,
                        bf16* __restrict__ W1t, bf16* __restrict__ U1t,
                        bf16* __restrict__ U2t) {
    const int l = blockIdx.y;
    const int n = blockIdx.x, k = threadIdx.x;
    const float* w1  = msg_w1 + (size_t)l * 257 * HID;
    const float* uw1 = upd_w1 + (size_t)l * 2 * HID * HID;
    const float* uw2 = upd_w2 + (size_t)l * HID * HID;
    if (n < 256) {
        W1t[(size_t)l * 256 * HID + n * HID + k] =
            (bf16)w1[(size_t)((n & 128) + k) * HID + (n & 127)];
    } else if (n < 384) {
        const int nn = n - 256;
        U1t[(size_t)l * HID * HID + nn * HID + k] = (bf16)uw1[(size_t)k * HID + nn];
    } else {
        const int nn = n - 384;
        U2t[(size_t)l * HID * HID + nn * HID + k] = (bf16)uw2[(size_t)k * HID + nn];
    }
}

// ---------------- W2Ut[l][j][k] = (w2 @ uw1_bot)[k][j]; b2u[l] = b2 @ uw1_bot ----------------
__global__ void k_small(const float* __restrict__ msg_w2, const float* __restrict__ upd_w1,
                        const float* __restrict__ msg_b2,
                        bf16* __restrict__ W2Ut, float* __restrict__ b2u) {
    __shared__ float row[HID];
    const int l = blockIdx.y;
    const int k = blockIdx.x, j = threadIdx.x;
    const float* w2  = msg_w2 + (size_t)l * HID * HID;
    const float* uw1 = upd_w1 + (size_t)l * 2 * HID * HID;
    const float* b2  = msg_b2 + (size_t)l * HID;
    const float* src = (k < HID) ? &w2[(size_t)k * HID] : b2;
    row[j] = src[j];
    __syncthreads();
    float acc = 0.f;
    #pragma unroll 8
    for (int m = 0; m < HID; ++m)
        acc = fmaf(row[m], uw1[(size_t)(HID + m) * HID + j], acc);
    if (k < HID) W2Ut[(size_t)l * HID * HID + (size_t)j * HID + k] = (bf16)acc;
    else b2u[l * HID + j] = acc;
}

// ---------------- fused embed + layer-0 pre (coalesced tile outputs) ----------------
__launch_bounds__(256, 4)
__global__ void k_embed_pre(const int* __restrict__ z, const float* __restrict__ embed,
                            const bf16* __restrict__ W1t, const float* __restrict__ b1,
                            bf16* __restrict__ h16, bf16* __restrict__ P, bf16* __restrict__ Q) {
    __shared__ bf16 sH[64 * 136];
    __shared__ bf16 sH2[64 * 136];
    const int tid = threadIdx.x;
    const int n0 = blockIdx.x * 64;
    {
        const int r = tid & 63, cg = tid >> 6;
        const int n = n0 + r;
        const bool valid = n < N_NODES;
        const float* src = valid ? &embed[(size_t)z[n] * HID + cg * 32] : embed;
        #pragma unroll
        for (int i = 0; i < 4; ++i) {
            bf16x8 v;
            if (valid) {
                v = cvt8(src + i * 8);
            } else {
                for (int j = 0; j < 8; ++j) v[j] = (bf16)0.f;
            }
            *(bf16x8*)&sH[r * 136 + cg * 32 + i * 8] = v;
        }
    }
    __syncthreads();
    tile_out(sH, h16, n0, tid);   // coalesced h16 write

    const int lane = tid & 63, wave = tid >> 6;
    const int lr = lane & 15, kq = (lane >> 4) * 8, rq = (lane >> 4) * 4;
    const int bcol = wave * 64;

    const f32x4 z4 = {0.f, 0.f, 0.f, 0.f};
    f32x4 acc[4][4];
    #pragma unroll
    for (int mi = 0; mi < 4; ++mi)
        #pragma unroll
        for (int ni = 0; ni < 4; ++ni) acc[mi][ni] = z4;

    #pragma unroll
    for (int ks = 0; ks < 4; ++ks) {
        bf16x8 av[4], bv[4];
        #pragma unroll
        for (int mi = 0; mi < 4; ++mi)
            av[mi] = *(const bf16x8*)&sH[(mi * 16 + lr) * 136 + ks * 32 + kq];
        #pragma unroll
        for (int ni = 0; ni < 4; ++ni)
            bv[ni] = *(const bf16x8*)&W1t[(size_t)(bcol + ni * 16 + lr) * HID + ks * 32 + kq];
        #pragma unroll
        for (int mi = 0; mi < 4; ++mi)
            #pragma unroll
            for (int ni = 0; ni < 4; ++ni)
                acc[mi][ni] = __builtin_amdgcn_mfma_f32_16x16x32_bf16(av[mi], bv[ni],
                                                                      acc[mi][ni], 0, 0, 0);
    }
    __syncthreads();   // all sH reads done; h16 copy done

    // stage: waves 0,1 -> P tile into sH; waves 2,3 -> Q tile into sH2
    {
        bf16* sOut = (bcol < 128) ? sH : sH2;
        const int cb = bcol & 127;
        #pragma unroll
        for (int ni = 0; ni < 4; ++ni) {
            const int c = cb + ni * 16 + lr;
            const float bias = (bcol >= 128) ? b1[c] : 0.f;
            #pragma unroll
            for (int mi = 0; mi < 4; ++mi)
                #pragma unroll
                for (int r = 0; r < 4; ++r)
                    sOut[(mi * 16 + rq + r) * 136 + c] = (bf16)(acc[mi][ni][r] + bias);
        }
    }
    __syncthreads();
    tile_out(sH, P, n0, tid);
    tile_out(sH2, Q, n0, tid);
}

// ---------------- fused layer (coalesced tile outputs) ----------------
template<int DO_PRE>
__launch_bounds__(256, 3)
__global__ void k_layer(bf16* __restrict__ h16,
                        const bf16* __restrict__ P, const bf16* __restrict__ Q,
                        const int* __restrict__ row_ptr, const int* __restrict__ s_src,
                        const float* __restrict__ s_attr, const float* __restrict__ w1last,
                        const bf16* __restrict__ U1t, const bf16* __restrict__ W2Ut,
                        const float* __restrict__ ub1, const float* __restrict__ b2u,
                        const bf16* __restrict__ U2t, const float* __restrict__ ub2,
                        const bf16* __restrict__ W1tn, const float* __restrict__ b1n,
                        bf16* __restrict__ Pn, bf16* __restrict__ Qn) {
    __shared__ bf16 sAgg[64 * 136];   // agg tile; then new-h (phase C in); then Q-out stage
    __shared__ bf16 sT[64 * 136];     // relu tile; then new-h out stage; then P-out stage
    __shared__ float sDeg[64];
    const int tid = threadIdx.x;
    const int n0 = blockIdx.x * 64;

    // ---- Phase A: aggregate incoming messages into sAgg (4x unrolled CSR gather) ----
    {
        const int grp = tid >> 4, ln = tid & 15, c8 = ln * 8;
        float wl[8];
        #pragma unroll
        for (int j = 0; j < 8; ++j) wl[j] = w1last[c8 + j];
        #pragma unroll
        for (int t = 0; t < 4; ++t) {
            const int row = t * 16 + grp;
            const int n = n0 + row;
            float a8[8];
            #pragma unroll
            for (int j = 0; j < 8; ++j) a8[j] = 0.f;
            if (n < N_NODES) {
                const int lo = row_ptr[n], hi = row_ptr[n + 1];
                if (ln == 0) sDeg[row] = (float)(hi - lo);
                const bf16x8 qv = *(const bf16x8*)&Q[(size_t)n * HID + c8];
                float q8[8];
                #pragma unroll
                for (int j = 0; j < 8; ++j) q8[j] = (float)qv[j];
                int e = lo;
                for (; e + 4 <= hi; e += 4) {
                    const int s0 = s_src[e], s1 = s_src[e + 1];
                    const int s2 = s_src[e + 2], s3 = s_src[e + 3];
                    const float t0 = s_attr[e], t1 = s_attr[e + 1];
                    const float t2 = s_attr[e + 2], t3 = s_attr[e + 3];
                    const bf16x8 p0 = *(const bf16x8*)&P[(size_t)s0 * HID + c8];
                    const bf16x8 p1 = *(const bf16x8*)&P[(size_t)s1 * HID + c8];
                    const bf16x8 p2 = *(const bf16x8*)&P[(size_t)s2 * HID + c8];
                    const bf16x8 p3 = *(const bf16x8*)&P[(size_t)s3 * HID + c8];
                    #pragma unroll
                    for (int j = 0; j < 8; ++j) {
                        a8[j] += fmaxf(fmaf(t0, wl[j], q8[j] + (float)p0[j]), 0.f);
                        a8[j] += fmaxf(fmaf(t1, wl[j], q8[j] + (float)p1[j]), 0.f);
                        a8[j] += fmaxf(fmaf(t2, wl[j], q8[j] + (float)p2[j]), 0.f);
                        a8[j] += fmaxf(fmaf(t3, wl[j], q8[j] + (float)p3[j]), 0.f);
                    }
                }
                for (; e < hi; ++e) {
                    const int s0 = s_src[e];
                    const float t0 = s_attr[e];
                    const bf16x8 p0 = *(const bf16x8*)&P[(size_t)s0 * HID + c8];
                    #pragma unroll
                    for (int j = 0; j < 8; ++j)
                        a8[j] += fmaxf(fmaf(t0, wl[j], q8[j] + (float)p0[j]), 0.f);
                }
            } else if (ln == 0) {
                sDeg[row] = 0.f;
            }
            bf16x8 o;
            #pragma unroll
            for (int j = 0; j < 8; ++j) o[j] = (bf16)a8[j];
            *(bf16x8*)&sAgg[row * 136 + c8] = o;
        }
    }
    __syncthreads();

    // ---- Phase B: acc = h16 @ U1t^T + agg @ W2Ut^T ----
    const int lane = tid & 63, wave = tid >> 6;
    const int lr = lane & 15, kq = (lane >> 4) * 8, rq = (lane >> 4) * 4;
    const int nw = wave * 32;
    const f32x4 z4 = {0.f, 0.f, 0.f, 0.f};

    f32x4 acc[4][2];
    #pragma unroll
    for (int mi = 0; mi < 4; ++mi) { acc[mi][0] = z4; acc[mi][1] = z4; }

    #pragma unroll
    for (int ks = 0; ks < 4; ++ks) {
        bf16x8 av[4], bv[2];
        #pragma unroll
        for (int mi = 0; mi < 4; ++mi)
            av[mi] = *(const bf16x8*)&h16[(size_t)(n0 + mi * 16 + lr) * HID + ks * 32 + kq];
        #pragma unroll
        for (int ni = 0; ni < 2; ++ni)
            bv[ni] = *(const bf16x8*)&U1t[(size_t)(nw + ni * 16 + lr) * HID + ks * 32 + kq];
        #pragma unroll
        for (int mi = 0; mi < 4; ++mi)
            #pragma unroll
            for (int ni = 0; ni < 2; ++ni)
                acc[mi][ni] = __builtin_amdgcn_mfma_f32_16x16x32_bf16(av[mi], bv[ni],
                                                                      acc[mi][ni], 0, 0, 0);
    }
    #pragma unroll
    for (int ks = 0; ks < 4; ++ks) {
        bf16x8 av[4], bv[2];
        #pragma unroll
        for (int mi = 0; mi < 4; ++mi)
            av[mi] = *(const bf16x8*)&sAgg[(mi * 16 + lr) * 136 + ks * 32 + kq];
        #pragma unroll
        for (int ni = 0; ni < 2; ++ni)
            bv[ni] = *(const bf16x8*)&W2Ut[(size_t)(nw + ni * 16 + lr) * HID + ks * 32 + kq];
        #pragma unroll
        for (int mi = 0; mi < 4; ++mi)
            #pragma unroll
            for (int ni = 0; ni < 2; ++ni)
                acc[mi][ni] = __builtin_amdgcn_mfma_f32_16x16x32_bf16(av[mi], bv[ni],
                                                                      acc[mi][ni], 0, 0, 0);
    }

    // bias + deg*b2u + relu -> sT
    #pragma unroll
    for (int ni = 0; ni < 2; ++ni) {
        const int c = nw + ni * 16 + lr;
        const float bb1 = ub1[c], bb2 = b2u[c];
        #pragma unroll
        for (int mi = 0; mi < 4; ++mi)
            #pragma unroll
            for (int r = 0; r < 4; ++r) {
                const int row = mi * 16 + rq + r;
                float v = acc[mi][ni][r] + bb1 + sDeg[row] * bb2;
                sT[row * 136 + c] = (bf16)fmaxf(v, 0.f);
            }
    }
    __syncthreads();   // sT ready

    // GEMM2: sT @ U2t^T
    f32x4 acc2[4][2];
    #pragma unroll
    for (int mi = 0; mi < 4; ++mi) { acc2[mi][0] = z4; acc2[mi][1] = z4; }
    #pragma unroll
    for (int ks = 0; ks < 4; ++ks) {
        bf16x8 av[4], bv[2];
        #pragma unroll
        for (int mi = 0; mi < 4; ++mi)
            av[mi] = *(const bf16x8*)&sT[(mi * 16 + lr) * 136 + ks * 32 + kq];
        #pragma unroll
        for (int ni = 0; ni < 2; ++ni)
            bv[ni] = *(const bf16x8*)&U2t[(size_t)(nw + ni * 16 + lr) * HID + ks * 32 + kq];
        #pragma unroll
        for (int mi = 0; mi < 4; ++mi)
            #pragma unroll
            for (int ni = 0; ni < 2; ++ni)
                acc2[mi][ni] = __builtin_amdgcn_mfma_f32_16x16x32_bf16(av[mi], bv[ni],
                                                                       acc2[mi][ni], 0, 0, 0);
    }
    __syncthreads();   // sT reads done; sAgg reads long done

    // epilogue: nh = h_old + acc2 + ub2 -> sT (h16-out stage) and sAgg (phase C input)
    #pragma unroll
    for (int ni = 0; ni < 2; ++ni) {
        const int c = nw + ni * 16 + lr;
        const float bb = ub2[c];
        #pragma unroll
        for (int mi = 0; mi < 4; ++mi)
            #pragma unroll
            for (int r = 0; r < 4; ++r) {
                const int row = mi * 16 + rq + r;
                const size_t off = (size_t)(n0 + row) * HID + c;
                const float nh = (float)h16[off] + acc2[mi][ni][r] + bb;
                sT[row * 136 + c] = (bf16)nh;
                if (DO_PRE) sAgg[row * 136 + c] = (bf16)nh;
            }
    }
    __syncthreads();
    tile_out(sT, h16, n0, tid);   // coalesced h16 writeback

    if (DO_PRE) {
        // ---- Phase C: next-layer [P|Q] = newh @ W1tn^T (A from sAgg) ----
        const int bcol = wave * 64;
        f32x4 pacc[4][4];
        #pragma unroll
        for (int mi = 0; mi < 4; ++mi)
            #pragma unroll
            for (int ni = 0; ni < 4; ++ni) pacc[mi][ni] = z4;

        #pragma unroll
        for (int ks = 0; ks < 4; ++ks) {
            bf16x8 av[4], bv[4];
            #pragma unroll
            for (int mi = 0; mi < 4; ++mi)
                av[mi] = *(const bf16x8*)&sAgg[(mi * 16 + lr) * 136 + ks * 32 + kq];
            #pragma unroll
            for (int ni = 0; ni < 4; ++ni)
                bv[ni] = *(const bf16x8*)&W1tn[(size_t)(bcol + ni * 16 + lr) * HID + ks * 32 + kq];
            #pragma unroll
            for (int mi = 0; mi < 4; ++mi)
                #pragma unroll
                for (int ni = 0; ni < 4; ++ni)
                    pacc[mi][ni] = __builtin_amdgcn_mfma_f32_16x16x32_bf16(av[mi], bv[ni],
                                                                           pacc[mi][ni], 0, 0, 0);
        }
        __syncthreads();   // h16 copy done (sT free), sAgg reads done

        // stage: waves 0,1 -> P into sT; waves 2,3 -> Q into sAgg
        {
            bf16* sOut = (bcol < 128) ? sT : sAgg;
            const int cb = bcol & 127;
            #pragma unroll
            for (int ni = 0; ni < 4; ++ni) {
                const int c = cb + ni * 16 + lr;
                const float bias = (bcol >= 128) ? b1n[c] : 0.f;
                #pragma unroll
                for (int mi = 0; mi < 4; ++mi)
                    #pragma unroll
                    for (int r = 0; r < 4; ++r)
                        sOut[(mi * 16 + rq + r) * 136 + c] = (bf16)(pacc[mi][ni][r] + bias);
            }
        }
        __syncthreads();
        tile_out(sT, Pn, n0, tid);
        tile_out(sAgg, Qn, n0, tid);
    }
}

// ---------------- pooling: contiguous 64-row tiles, run-flush per graph segment -------------
__global__ void k_pool(const bf16* __restrict__ h16, const int* __restrict__ batch,
                       float* __restrict__ pooled) {
    const int n0 = blockIdx.x * 64;
    const int c = threadIdx.x & 127;
    const int half = threadIdx.x >> 7;
    int cur = -1;
    float s = 0.f;
    const int rbeg = n0 + half * 32;
    const int rend = min(rbeg + 32, N_NODES);
    for (int n = rbeg; n < rend; ++n) {
        const int g = batch[n];
        const float v = (float)h16[(size_t)n * HID + c];
        if (g != cur) {
            if (cur >= 0) atomicAdd(&pooled[cur * HID + c], s);
            cur = g; s = v;
        } else {
            s += v;
        }
    }
    if (cur >= 0) atomicAdd(&pooled[cur * HID + c], s);
}

// ---------------- head MLP (fp32); counts via binary search on sorted batch ----------------
__device__ inline int lb(const int* a, int n, int v) {
    int lo = 0, hi = n;
    while (lo < hi) { int m = (lo + hi) >> 1; if (a[m] < v) lo = m + 1; else hi = m; }
    return lo;
}

__global__ void k_head(const float* __restrict__ pooled, const int* __restrict__ batch,
                       const float* __restrict__ hw1, const float* __restrict__ hb1,
                       const float* __restrict__ hw2, const float* __restrict__ hb2,
                       float* __restrict__ out) {
    const int g = blockIdx.x;
    const int c = threadIdx.x;
    __shared__ float sp[HID];
    __shared__ float red[HID];
    __shared__ int sb[2];
    if (c == 0) { sb[0] = lb(batch, N_NODES, g); sb[1] = lb(batch, N_NODES, g + 1); }
    __syncthreads();
    const float cnt = fmaxf((float)(sb[1] - sb[0]), 1.f);
    sp[c] = pooled[g * HID + c] / cnt;
    __syncthreads();
    float acc = hb1[c];
    #pragma unroll 8
    for (int k = 0; k < HID; ++k) acc = fmaf(sp[k], hw1[k * HID + c], acc);
    red[c] = fmaxf(acc, 0.f) * hw2[c];
    __syncthreads();
    for (int s = 64; s > 0; s >>= 1) {
        if (c < s) red[c] += red[c + s];
        __syncthreads();
    }
    if (c == 0) out[g] = red[0] + hb2[0];
}

extern "C" void kernel_launch(void* const* d_in, const int* in_sizes, int n_in,
                              void* d_out, int out_size, void* d_ws, size_t ws_size,
                              hipStream_t stream) {
    const int*   z       = (const int*)d_in[0];
    const int*   ei      = (const int*)d_in[1];
    const float* eattr   = (const float*)d_in[2];
    const int*   batch   = (const int*)d_in[3];
    const float* embed   = (const float*)d_in[4];
    const float* msg_w1  = (const float*)d_in[5];
    const float* msg_b1  = (const float*)d_in[6];
    const float* msg_w2  = (const float*)d_in[7];
    const float* msg_b2  = (const float*)d_in[8];
    const float* upd_w1  = (const float*)d_in[9];
    const float* upd_b1  = (const float*)d_in[10];
    const float* upd_w2  = (const float*)d_in[11];
    const float* upd_b2  = (const float*)d_in[12];
    const float* head_w1 = (const float*)d_in[13];
    const float* head_b1 = (const float*)d_in[14];
    const float* head_w2 = (const float*)d_in[15];
    const float* head_b2 = (const float*)d_in[16];
    float* out = (float*)d_out;

    // workspace layout (~68 MB)
    float* pooled = (float*)d_ws;                       // 64 x 128
    float* b2u    = pooled + NUM_GRAPHS * HID;          // 3 x 128
    float* s_attr = b2u + 3 * HID;                      // E
    int* deg_i    = (int*)(s_attr + N_EDGES);
    int* row_ptr  = deg_i + N_NODES;                    // N+1
    int* partial  = row_ptr + N_NODES + 1;              // 256
    int* cursor   = partial + 256;                      // N
    int* s_src    = cursor + N_NODES;                   // E
    bf16* h16     = (bf16*)((((unsigned long long)(s_src + N_EDGES)) + 15ULL) & ~15ULL);
    bf16* P0      = h16 + (size_t)NPAD * HID;
    bf16* Q0      = P0 + (size_t)NPAD * HID;
    bf16* P1      = Q0 + (size_t)NPAD * HID;
    bf16* Q1      = P1 + (size_t)NPAD * HID;
    bf16* W1t     = Q1 + (size_t)NPAD * HID;            // 3 x 256 x 128
    bf16* U1t     = W1t + 3 * 256 * HID;                // 3 x 128 x 128
    bf16* W2Ut    = U1t + 3 * HID * HID;
    bf16* U2t     = W2Ut + 3 * HID * HID;

    const int* esrc = ei;
    const int* edst = ei + N_EDGES;

    // CSR build + all-layer weight prep
    hipMemsetAsync(deg_i, 0, N_NODES * sizeof(int), stream);
    k_hist<<<(N_EDGES + 255) / 256, 256, 0, stream>>>(edst, deg_i);
    k_scan1<<<SCAN_B, 256, 0, stream>>>(deg_i, partial);
    k_scan2<<<1, 256, 0, stream>>>(partial, row_ptr);
    k_scan3<<<SCAN_B, 256, 0, stream>>>(deg_i, partial, row_ptr, cursor);
    k_scatter<<<(N_EDGES + 255) / 256, 256, 0, stream>>>(esrc, edst, eattr, cursor, s_src, s_attr);
    {
        dim3 g1(512, 3);
        k_wprep<<<g1, 128, 0, stream>>>(msg_w1, upd_w1, upd_w2, W1t, U1t, U2t);
        dim3 g2(HID + 1, 3);
        k_small<<<g2, HID, 0, stream>>>(msg_w2, upd_w1, msg_b2, W2Ut, b2u);
    }

    const int nblk = NPAD / 64;
    // embed + layer-0 pre
    k_embed_pre<<<nblk, 256, 0, stream>>>(z, embed, W1t, msg_b1, h16, P0, Q0);

    bf16* Pa = P0; bf16* Qa = Q0; bf16* Pb = P1; bf16* Qb = Q1;
    for (int l = 0; l < 3; ++l) {
        const float* w1last = msg_w1 + (size_t)l * 257 * HID + 256 * HID;
        const bf16* U1l  = U1t  + (size_t)l * HID * HID;
        const bf16* W2Ul = W2Ut + (size_t)l * HID * HID;
        const bf16* U2l  = U2t  + (size_t)l * HID * HID;
        if (l < 2) {
            k_layer<1><<<nblk, 256, 0, stream>>>(
                h16, Pa, Qa, row_ptr, s_src, s_attr, w1last,
                U1l, W2Ul, upd_b1 + (size_t)l * HID, b2u + l * HID,
                U2l, upd_b2 + (size_t)l * HID,
                W1t + (size_t)(l + 1) * 256 * HID, msg_b1 + (size_t)(l + 1) * HID, Pb, Qb);
            bf16* tp = Pa; Pa = Pb; Pb = tp;
            bf16* tq = Qa; Qa = Qb; Qb = tq;
        } else {
            k_layer<0><<<nblk, 256, 0, stream>>>(
                h16, Pa, Qa, row_ptr, s_src, s_attr, w1last,
                U1l, W2Ul, upd_b1 + (size_t)l * HID, b2u + l * HID,
                U2l, upd_b2 + (size_t)l * HID,
                nullptr, nullptr, nullptr, nullptr);
        }
    }
    hipMemsetAsync(pooled, 0, NUM_GRAPHS * HID * sizeof(float), stream);
    k_pool<<<nblk, 256, 0, stream>>>(h16, batch, pooled);
    k_head<<<NUM_GRAPHS, 128, 0, stream>>>(pooled, batch, head_w1, head_b1, head_w2, head_b2, out);
}

// Round 9
// 264.480 us; speedup vs baseline: 18.8732x; 1.1944x over previous
//
#include <hip/hip_runtime.h>

#define N_NODES 50000
#define NPAD 50048          // 782 * 64
#define N_EDGES 400000
#define HID 128
#define NUM_GRAPHS 64
#define SCAN_B 196          // ceil(N_NODES/256)
#define ECAP 2048           // LDS edge-metadata capacity per block (avg 512)

typedef __bf16 bf16;
typedef bf16 bf16x8 __attribute__((ext_vector_type(8)));
typedef float f32x4 __attribute__((ext_vector_type(4)));

__device__ inline bf16x8 cvt8(const float* p) {
    const float4 a = *(const float4*)p;
    const float4 b = *(const float4*)(p + 4);
    bf16x8 v;
    v[0] = (bf16)a.x; v[1] = (bf16)a.y; v[2] = (bf16)a.z; v[3] = (bf16)a.w;
    v[4] = (bf16)b.x; v[5] = (bf16)b.y; v[6] = (bf16)b.z; v[7] = (bf16)b.w;
    return v;
}

// coalesced 64x128 bf16 tile copy: LDS(ld=136) -> global rows n0..n0+63
__device__ __forceinline__ void tile_out(const bf16* lds, bf16* g, int n0, int tid) {
    #pragma unroll
    for (int u = 0; u < 4; ++u) {
        const int unit = u * 256 + tid;          // 0..1023
        const int row = unit >> 4;
        const int ci = (unit & 15) * 8;
        *(bf16x8*)&g[(size_t)(n0 + row) * HID + ci] =
            *(const bf16x8*)&lds[row * 136 + ci];
    }
}

// ---------------- CSR build ----------------
__global__ void k_hist(const int* __restrict__ edst, int* __restrict__ deg) {
    int e = blockIdx.x * 256 + threadIdx.x;
    if (e < N_EDGES) atomicAdd(&deg[edst[e]], 1);
}

__global__ void k_scan1(const int* __restrict__ deg, int* __restrict__ partial) {
    __shared__ int buf[256];
    int i = blockIdx.x * 256 + threadIdx.x;
    buf[threadIdx.x] = (i < N_NODES) ? deg[i] : 0;
    __syncthreads();
    for (int off = 128; off > 0; off >>= 1) {
        if (threadIdx.x < off) buf[threadIdx.x] += buf[threadIdx.x + off];
        __syncthreads();
    }
    if (threadIdx.x == 0) partial[blockIdx.x] = buf[0];
}

__global__ void k_scan2(int* __restrict__ partial, int* __restrict__ row_ptr) {
    __shared__ int buf[256];
    int v = (threadIdx.x < SCAN_B) ? partial[threadIdx.x] : 0;
    buf[threadIdx.x] = v;
    __syncthreads();
    for (int off = 1; off < 256; off <<= 1) {
        int t = (threadIdx.x >= off) ? buf[threadIdx.x - off] : 0;
        __syncthreads();
        buf[threadIdx.x] += t;
        __syncthreads();
    }
    if (threadIdx.x < SCAN_B) partial[threadIdx.x] = buf[threadIdx.x] - v;  // exclusive
    if (threadIdx.x == 255) row_ptr[N_NODES] = buf[255];
}

__global__ void k_scan3(const int* __restrict__ deg, const int* __restrict__ partial,
                        int* __restrict__ row_ptr, int* __restrict__ cursor) {
    __shared__ int buf[256];
    int i = blockIdx.x * 256 + threadIdx.x;
    int v = (i < N_NODES) ? deg[i] : 0;
    buf[threadIdx.x] = v;
    __syncthreads();
    for (int off = 1; off < 256; off <<= 1) {
        int t = (threadIdx.x >= off) ? buf[threadIdx.x - off] : 0;
        __syncthreads();
        buf[threadIdx.x] += t;
        __syncthreads();
    }
    if (i < N_NODES) {
        int ex = partial[blockIdx.x] + buf[threadIdx.x] - v;
        row_ptr[i] = ex;
        cursor[i] = ex;
    }
}

__global__ void k_scatter(const int* __restrict__ esrc, const int* __restrict__ edst,
                          const float* __restrict__ attr, int* __restrict__ cursor,
                          int* __restrict__ s_src, float* __restrict__ s_attr) {
    int e = blockIdx.x * 256 + threadIdx.x;
    if (e >= N_EDGES) return;
    int p = atomicAdd(&cursor[edst[e]], 1);
    s_src[p] = esrc[e];
    s_attr[p] = attr[e];
}

// ---------------- weight prep (all layers upfront): bf16 [n][k] transposes ----------------
__global__ void k_wprep(const float* __restrict__ msg_w1, const float* __restrict__ upd_w1,
                        const float* __restrict__ upd_w2,
                        bf16* __restrict__ W1t, bf16* __restrict__ U1t,
                        bf16* __restrict__ U2t) {
    const int l = blockIdx.y;
    const int n = blockIdx.x, k = threadIdx.x;
    const float* w1  = msg_w1 + (size_t)l * 257 * HID;
    const float* uw1 = upd_w1 + (size_t)l * 2 * HID * HID;
    const float* uw2 = upd_w2 + (size_t)l * HID * HID;
    if (n < 256) {
        W1t[(size_t)l * 256 * HID + n * HID + k] =
            (bf16)w1[(size_t)((n & 128) + k) * HID + (n & 127)];
    } else if (n < 384) {
        const int nn = n - 256;
        U1t[(size_t)l * HID * HID + nn * HID + k] = (bf16)uw1[(size_t)k * HID + nn];
    } else {
        const int nn = n - 384;
        U2t[(size_t)l * HID * HID + nn * HID + k] = (bf16)uw2[(size_t)k * HID + nn];
    }
}

// ---------------- W2Ut[l][j][k] = (w2 @ uw1_bot)[k][j]; b2u[l] = b2 @ uw1_bot ----------------
__global__ void k_small(const float* __restrict__ msg_w2, const float* __restrict__ upd_w1,
                        const float* __restrict__ msg_b2,
                        bf16* __restrict__ W2Ut, float* __restrict__ b2u) {
    __shared__ float row[HID];
    const int l = blockIdx.y;
    const int k = blockIdx.x, j = threadIdx.x;
    const float* w2  = msg_w2 + (size_t)l * HID * HID;
    const float* uw1 = upd_w1 + (size_t)l * 2 * HID * HID;
    const float* b2  = msg_b2 + (size_t)l * HID;
    const float* src = (k < HID) ? &w2[(size_t)k * HID] : b2;
    row[j] = src[j];
    __syncthreads();
    float acc = 0.f;
    #pragma unroll 8
    for (int m = 0; m < HID; ++m)
        acc = fmaf(row[m], uw1[(size_t)(HID + m) * HID + j], acc);
    if (k < HID) W2Ut[(size_t)l * HID * HID + (size_t)j * HID + k] = (bf16)acc;
    else b2u[l * HID + j] = acc;
}

// ---------------- fused embed + layer-0 pre (coalesced tile outputs) ----------------
__launch_bounds__(256, 4)
__global__ void k_embed_pre(const int* __restrict__ z, const float* __restrict__ embed,
                            const bf16* __restrict__ W1t, const float* __restrict__ b1,
                            bf16* __restrict__ h16, bf16* __restrict__ P, bf16* __restrict__ Q) {
    __shared__ bf16 sH[64 * 136];
    __shared__ bf16 sH2[64 * 136];
    const int tid = threadIdx.x;
    const int n0 = blockIdx.x * 64;
    {
        const int r = tid & 63, cg = tid >> 6;
        const int n = n0 + r;
        const bool valid = n < N_NODES;
        const float* src = valid ? &embed[(size_t)z[n] * HID + cg * 32] : embed;
        #pragma unroll
        for (int i = 0; i < 4; ++i) {
            bf16x8 v;
            if (valid) {
                v = cvt8(src + i * 8);
            } else {
                for (int j = 0; j < 8; ++j) v[j] = (bf16)0.f;
            }
            *(bf16x8*)&sH[r * 136 + cg * 32 + i * 8] = v;
        }
    }
    __syncthreads();
    tile_out(sH, h16, n0, tid);   // coalesced h16 write

    const int lane = tid & 63, wave = tid >> 6;
    const int lr = lane & 15, kq = (lane >> 4) * 8, rq = (lane >> 4) * 4;
    const int bcol = wave * 64;

    const f32x4 z4 = {0.f, 0.f, 0.f, 0.f};
    f32x4 acc[4][4];
    #pragma unroll
    for (int mi = 0; mi < 4; ++mi)
        #pragma unroll
        for (int ni = 0; ni < 4; ++ni) acc[mi][ni] = z4;

    #pragma unroll
    for (int ks = 0; ks < 4; ++ks) {
        bf16x8 av[4], bv[4];
        #pragma unroll
        for (int mi = 0; mi < 4; ++mi)
            av[mi] = *(const bf16x8*)&sH[(mi * 16 + lr) * 136 + ks * 32 + kq];
        #pragma unroll
        for (int ni = 0; ni < 4; ++ni)
            bv[ni] = *(const bf16x8*)&W1t[(size_t)(bcol + ni * 16 + lr) * HID + ks * 32 + kq];
        #pragma unroll
        for (int mi = 0; mi < 4; ++mi)
            #pragma unroll
            for (int ni = 0; ni < 4; ++ni)
                acc[mi][ni] = __builtin_amdgcn_mfma_f32_16x16x32_bf16(av[mi], bv[ni],
                                                                      acc[mi][ni], 0, 0, 0);
    }
    __syncthreads();   // all sH reads done; h16 copy done

    // stage: waves 0,1 -> P tile into sH; waves 2,3 -> Q tile into sH2
    {
        bf16* sOut = (bcol < 128) ? sH : sH2;
        const int cb = bcol & 127;
        #pragma unroll
        for (int ni = 0; ni < 4; ++ni) {
            const int c = cb + ni * 16 + lr;
            const float bias = (bcol >= 128) ? b1[c] : 0.f;
            #pragma unroll
            for (int mi = 0; mi < 4; ++mi)
                #pragma unroll
                for (int r = 0; r < 4; ++r)
                    sOut[(mi * 16 + rq + r) * 136 + c] = (bf16)(acc[mi][ni][r] + bias);
        }
    }
    __syncthreads();
    tile_out(sH, P, n0, tid);
    tile_out(sH2, Q, n0, tid);
}

// ---------------- fused layer (LDS edge metadata + coalesced tile outputs) ----------------
template<int DO_PRE>
__launch_bounds__(256, 4)
__global__ void k_layer(bf16* __restrict__ h16,
                        const bf16* __restrict__ P, const bf16* __restrict__ Q,
                        const int* __restrict__ row_ptr, const int* __restrict__ s_src,
                        const float* __restrict__ s_attr, const float* __restrict__ w1last,
                        const bf16* __restrict__ U1t, const bf16* __restrict__ W2Ut,
                        const float* __restrict__ ub1, const float* __restrict__ b2u,
                        const bf16* __restrict__ U2t, const float* __restrict__ ub2,
                        const bf16* __restrict__ W1tn, const float* __restrict__ b1n,
                        bf16* __restrict__ Pn, bf16* __restrict__ Qn) {
    __shared__ bf16 sAgg[64 * 136];   // agg tile; then new-h (phase C in); then Q-out stage
    __shared__ bf16 sT[64 * 136];     // edge meta (phase A); relu tile; h-out; P-out stage
    __shared__ float sDeg[64];
    const int tid = threadIdx.x;
    const int n0 = blockIdx.x * 64;

    // ---- Phase A: stage edge metadata in LDS, then gather-aggregate into sAgg ----
    {
        int*   sEsrc = (int*)sT;              // ECAP*4 B = ECAP*2 bf16
        float* sEatt = (float*)(sT + ECAP * 2);
        const int elo = row_ptr[n0];
        const int ehi = row_ptr[min(n0 + 64, N_NODES)];
        const int ecap = min(ehi - elo, ECAP);
        for (int i = tid; i < ecap; i += 256) {
            sEsrc[i] = s_src[elo + i];
            sEatt[i] = s_attr[elo + i];
        }
        __syncthreads();

        const int grp = tid >> 4, ln = tid & 15, c8 = ln * 8;
        float wl[8];
        #pragma unroll
        for (int j = 0; j < 8; ++j) wl[j] = w1last[c8 + j];
        #pragma unroll
        for (int t = 0; t < 4; ++t) {
            const int row = t * 16 + grp;
            const int n = n0 + row;
            float a8[8];
            #pragma unroll
            for (int j = 0; j < 8; ++j) a8[j] = 0.f;
            if (n < N_NODES) {
                const int lo = row_ptr[n], hi = row_ptr[n + 1];
                if (ln == 0) sDeg[row] = (float)(hi - lo);
                const bf16x8 qv = *(const bf16x8*)&Q[(size_t)n * HID + c8];
                float q8[8];
                #pragma unroll
                for (int j = 0; j < 8; ++j) q8[j] = (float)qv[j];
                const int llo = lo - elo, lhi = hi - elo;
                if (lhi <= ecap) {
                    // fast path: metadata from LDS; only P-gather hits memory
                    int e = llo;
                    for (; e + 4 <= lhi; e += 4) {
                        const int s0 = sEsrc[e], s1 = sEsrc[e + 1];
                        const int s2 = sEsrc[e + 2], s3 = sEsrc[e + 3];
                        const float t0 = sEatt[e], t1 = sEatt[e + 1];
                        const float t2 = sEatt[e + 2], t3 = sEatt[e + 3];
                        const bf16x8 p0 = *(const bf16x8*)&P[(size_t)s0 * HID + c8];
                        const bf16x8 p1 = *(const bf16x8*)&P[(size_t)s1 * HID + c8];
                        const bf16x8 p2 = *(const bf16x8*)&P[(size_t)s2 * HID + c8];
                        const bf16x8 p3 = *(const bf16x8*)&P[(size_t)s3 * HID + c8];
                        #pragma unroll
                        for (int j = 0; j < 8; ++j) {
                            a8[j] += fmaxf(fmaf(t0, wl[j], q8[j] + (float)p0[j]), 0.f);
                            a8[j] += fmaxf(fmaf(t1, wl[j], q8[j] + (float)p1[j]), 0.f);
                            a8[j] += fmaxf(fmaf(t2, wl[j], q8[j] + (float)p2[j]), 0.f);
                            a8[j] += fmaxf(fmaf(t3, wl[j], q8[j] + (float)p3[j]), 0.f);
                        }
                    }
                    for (; e < lhi; ++e) {
                        const int s0 = sEsrc[e];
                        const float t0 = sEatt[e];
                        const bf16x8 p0 = *(const bf16x8*)&P[(size_t)s0 * HID + c8];
                        #pragma unroll
                        for (int j = 0; j < 8; ++j)
                            a8[j] += fmaxf(fmaf(t0, wl[j], q8[j] + (float)p0[j]), 0.f);
                    }
                } else {
                    // fallback: metadata from global (rare)
                    for (int e = lo; e < hi; ++e) {
                        const int s0 = s_src[e];
                        const float t0 = s_attr[e];
                        const bf16x8 p0 = *(const bf16x8*)&P[(size_t)s0 * HID + c8];
                        #pragma unroll
                        for (int j = 0; j < 8; ++j)
                            a8[j] += fmaxf(fmaf(t0, wl[j], q8[j] + (float)p0[j]), 0.f);
                    }
                }
            } else if (ln == 0) {
                sDeg[row] = 0.f;
            }
            bf16x8 o;
            #pragma unroll
            for (int j = 0; j < 8; ++j) o[j] = (bf16)a8[j];
            *(bf16x8*)&sAgg[row * 136 + c8] = o;
        }
    }
    __syncthreads();

    // ---- Phase B: acc = h16 @ U1t^T + agg @ W2Ut^T ----
    const int lane = tid & 63, wave = tid >> 6;
    const int lr = lane & 15, kq = (lane >> 4) * 8, rq = (lane >> 4) * 4;
    const int nw = wave * 32;
    const f32x4 z4 = {0.f, 0.f, 0.f, 0.f};

    f32x4 acc[4][2];
    #pragma unroll
    for (int mi = 0; mi < 4; ++mi) { acc[mi][0] = z4; acc[mi][1] = z4; }

    #pragma unroll
    for (int ks = 0; ks < 4; ++ks) {
        bf16x8 av[4], bv[2];
        #pragma unroll
        for (int mi = 0; mi < 4; ++mi)
            av[mi] = *(const bf16x8*)&h16[(size_t)(n0 + mi * 16 + lr) * HID + ks * 32 + kq];
        #pragma unroll
        for (int ni = 0; ni < 2; ++ni)
            bv[ni] = *(const bf16x8*)&U1t[(size_t)(nw + ni * 16 + lr) * HID + ks * 32 + kq];
        #pragma unroll
        for (int mi = 0; mi < 4; ++mi)
            #pragma unroll
            for (int ni = 0; ni < 2; ++ni)
                acc[mi][ni] = __builtin_amdgcn_mfma_f32_16x16x32_bf16(av[mi], bv[ni],
                                                                      acc[mi][ni], 0, 0, 0);
    }
    #pragma unroll
    for (int ks = 0; ks < 4; ++ks) {
        bf16x8 av[4], bv[2];
        #pragma unroll
        for (int mi = 0; mi < 4; ++mi)
            av[mi] = *(const bf16x8*)&sAgg[(mi * 16 + lr) * 136 + ks * 32 + kq];
        #pragma unroll
        for (int ni = 0; ni < 2; ++ni)
            bv[ni] = *(const bf16x8*)&W2Ut[(size_t)(nw + ni * 16 + lr) * HID + ks * 32 + kq];
        #pragma unroll
        for (int mi = 0; mi < 4; ++mi)
            #pragma unroll
            for (int ni = 0; ni < 2; ++ni)
                acc[mi][ni] = __builtin_amdgcn_mfma_f32_16x16x32_bf16(av[mi], bv[ni],
                                                                      acc[mi][ni], 0, 0, 0);
    }
    __syncthreads();   // meta reads done (sT free for relu tile)

    // bias + deg*b2u + relu -> sT
    #pragma unroll
    for (int ni = 0; ni < 2; ++ni) {
        const int c = nw + ni * 16 + lr;
        const float bb1 = ub1[c], bb2 = b2u[c];
        #pragma unroll
        for (int mi = 0; mi < 4; ++mi)
            #pragma unroll
            for (int r = 0; r < 4; ++r) {
                const int row = mi * 16 + rq + r;
                float v = acc[mi][ni][r] + bb1 + sDeg[row] * bb2;
                sT[row * 136 + c] = (bf16)fmaxf(v, 0.f);
            }
    }
    __syncthreads();   // sT ready

    // GEMM2: sT @ U2t^T
    f32x4 acc2[4][2];
    #pragma unroll
    for (int mi = 0; mi < 4; ++mi) { acc2[mi][0] = z4; acc2[mi][1] = z4; }
    #pragma unroll
    for (int ks = 0; ks < 4; ++ks) {
        bf16x8 av[4], bv[2];
        #pragma unroll
        for (int mi = 0; mi < 4; ++mi)
            av[mi] = *(const bf16x8*)&sT[(mi * 16 + lr) * 136 + ks * 32 + kq];
        #pragma unroll
        for (int ni = 0; ni < 2; ++ni)
            bv[ni] = *(const bf16x8*)&U2t[(size_t)(nw + ni * 16 + lr) * HID + ks * 32 + kq];
        #pragma unroll
        for (int mi = 0; mi < 4; ++mi)
            #pragma unroll
            for (int ni = 0; ni < 2; ++ni)
                acc2[mi][ni] = __builtin_amdgcn_mfma_f32_16x16x32_bf16(av[mi], bv[ni],
                                                                       acc2[mi][ni], 0, 0, 0);
    }
    __syncthreads();   // sT reads done

    // epilogue: nh = h_old + acc2 + ub2 -> sT (h16-out stage) and sAgg (phase C input)
    #pragma unroll
    for (int ni = 0; ni < 2; ++ni) {
        const int c = nw + ni * 16 + lr;
        const float bb = ub2[c];
        #pragma unroll
        for (int mi = 0; mi < 4; ++mi)
            #pragma unroll
            for (int r = 0; r < 4; ++r) {
                const int row = mi * 16 + rq + r;
                const size_t off = (size_t)(n0 + row) * HID + c;
                const float nh = (float)h16[off] + acc2[mi][ni][r] + bb;
                sT[row * 136 + c] = (bf16)nh;
                if (DO_PRE) sAgg[row * 136 + c] = (bf16)nh;
            }
    }
    __syncthreads();
    tile_out(sT, h16, n0, tid);   // coalesced h16 writeback

    if (DO_PRE) {
        // ---- Phase C: next-layer [P|Q] = newh @ W1tn^T (A from sAgg) ----
        const int bcol = wave * 64;
        f32x4 pacc[4][4];
        #pragma unroll
        for (int mi = 0; mi < 4; ++mi)
            #pragma unroll
            for (int ni = 0; ni < 4; ++ni) pacc[mi][ni] = z4;

        #pragma unroll
        for (int ks = 0; ks < 4; ++ks) {
            bf16x8 av[4], bv[4];
            #pragma unroll
            for (int mi = 0; mi < 4; ++mi)
                av[mi] = *(const bf16x8*)&sAgg[(mi * 16 + lr) * 136 + ks * 32 + kq];
            #pragma unroll
            for (int ni = 0; ni < 4; ++ni)
                bv[ni] = *(const bf16x8*)&W1tn[(size_t)(bcol + ni * 16 + lr) * HID + ks * 32 + kq];
            #pragma unroll
            for (int mi = 0; mi < 4; ++mi)
                #pragma unroll
                for (int ni = 0; ni < 4; ++ni)
                    pacc[mi][ni] = __builtin_amdgcn_mfma_f32_16x16x32_bf16(av[mi], bv[ni],
                                                                           pacc[mi][ni], 0, 0, 0);
        }
        __syncthreads();   // h16 copy done (sT free), sAgg reads done

        // stage: waves 0,1 -> P into sT; waves 2,3 -> Q into sAgg
        {
            bf16* sOut = (bcol < 128) ? sT : sAgg;
            const int cb = bcol & 127;
            #pragma unroll
            for (int ni = 0; ni < 4; ++ni) {
                const int c = cb + ni * 16 + lr;
                const float bias = (bcol >= 128) ? b1n[c] : 0.f;
                #pragma unroll
                for (int mi = 0; mi < 4; ++mi)
                    #pragma unroll
                    for (int r = 0; r < 4; ++r)
                        sOut[(mi * 16 + rq + r) * 136 + c] = (bf16)(pacc[mi][ni][r] + bias);
            }
        }
        __syncthreads();
        tile_out(sT, Pn, n0, tid);
        tile_out(sAgg, Qn, n0, tid);
    }
}

// ---------------- pooling: contiguous 64-row tiles, run-flush per graph segment -------------
__global__ void k_pool(const bf16* __restrict__ h16, const int* __restrict__ batch,
                       float* __restrict__ pooled) {
    const int n0 = blockIdx.x * 64;
    const int c = threadIdx.x & 127;
    const int half = threadIdx.x >> 7;
    int cur = -1;
    float s = 0.f;
    const int rbeg = n0 + half * 32;
    const int rend = min(rbeg + 32, N_NODES);
    for (int n = rbeg; n < rend; ++n) {
        const int g = batch[n];
        const float v = (float)h16[(size_t)n * HID + c];
        if (g != cur) {
            if (cur >= 0) atomicAdd(&pooled[cur * HID + c], s);
            cur = g; s = v;
        } else {
            s += v;
        }
    }
    if (cur >= 0) atomicAdd(&pooled[cur * HID + c], s);
}

// ---------------- head MLP (fp32); counts via binary search on sorted batch ----------------
__device__ inline int lb(const int* a, int n, int v) {
    int lo = 0, hi = n;
    while (lo < hi) { int m = (lo + hi) >> 1; if (a[m] < v) lo = m + 1; else hi = m; }
    return lo;
}

__global__ void k_head(const float* __restrict__ pooled, const int* __restrict__ batch,
                       const float* __restrict__ hw1, const float* __restrict__ hb1,
                       const float* __restrict__ hw2, const float* __restrict__ hb2,
                       float* __restrict__ out) {
    const int g = blockIdx.x;
    const int c = threadIdx.x;
    __shared__ float sp[HID];
    __shared__ float red[HID];
    __shared__ int sb[2];
    if (c == 0) { sb[0] = lb(batch, N_NODES, g); sb[1] = lb(batch, N_NODES, g + 1); }
    __syncthreads();
    const float cnt = fmaxf((float)(sb[1] - sb[0]), 1.f);
    sp[c] = pooled[g * HID + c] / cnt;
    __syncthreads();
    float acc = hb1[c];
    #pragma unroll 8
    for (int k = 0; k < HID; ++k) acc = fmaf(sp[k], hw1[k * HID + c], acc);
    red[c] = fmaxf(acc, 0.f) * hw2[c];
    __syncthreads();
    for (int s = 64; s > 0; s >>= 1) {
        if (c < s) red[c] += red[c + s];
        __syncthreads();
    }
    if (c == 0) out[g] = red[0] + hb2[0];
}

extern "C" void kernel_launch(void* const* d_in, const int* in_sizes, int n_in,
                              void* d_out, int out_size, void* d_ws, size_t ws_size,
                              hipStream_t stream) {
    const int*   z       = (const int*)d_in[0];
    const int*   ei      = (const int*)d_in[1];
    const float* eattr   = (const float*)d_in[2];
    const int*   batch   = (const int*)d_in[3];
    const float* embed   = (const float*)d_in[4];
    const float* msg_w1  = (const float*)d_in[5];
    const float* msg_b1  = (const float*)d_in[6];
    const float* msg_w2  = (const float*)d_in[7];
    const float* msg_b2  = (const float*)d_in[8];
    const float* upd_w1  = (const float*)d_in[9];
    const float* upd_b1  = (const float*)d_in[10];
    const float* upd_w2  = (const float*)d_in[11];
    const float* upd_b2  = (const float*)d_in[12];
    const float* head_w1 = (const float*)d_in[13];
    const float* head_b1 = (const float*)d_in[14];
    const float* head_w2 = (const float*)d_in[15];
    const float* head_b2 = (const float*)d_in[16];
    float* out = (float*)d_out;

    // workspace layout (~68 MB)
    float* pooled = (float*)d_ws;                       // 64 x 128
    float* b2u    = pooled + NUM_GRAPHS * HID;          // 3 x 128
    float* s_attr = b2u + 3 * HID;                      // E
    int* deg_i    = (int*)(s_attr + N_EDGES);
    int* row_ptr  = deg_i + N_NODES;                    // N+1
    int* partial  = row_ptr + N_NODES + 1;              // 256
    int* cursor   = partial + 256;                      // N
    int* s_src    = cursor + N_NODES;                   // E
    bf16* h16     = (bf16*)((((unsigned long long)(s_src + N_EDGES)) + 15ULL) & ~15ULL);
    bf16* P0      = h16 + (size_t)NPAD * HID;
    bf16* Q0      = P0 + (size_t)NPAD * HID;
    bf16* P1      = Q0 + (size_t)NPAD * HID;
    bf16* Q1      = P1 + (size_t)NPAD * HID;
    bf16* W1t     = Q1 + (size_t)NPAD * HID;            // 3 x 256 x 128
    bf16* U1t     = W1t + 3 * 256 * HID;                // 3 x 128 x 128
    bf16* W2Ut    = U1t + 3 * HID * HID;
    bf16* U2t     = W2Ut + 3 * HID * HID;

    const int* esrc = ei;
    const int* edst = ei + N_EDGES;

    // CSR build + all-layer weight prep
    hipMemsetAsync(deg_i, 0, N_NODES * sizeof(int), stream);
    k_hist<<<(N_EDGES + 255) / 256, 256, 0, stream>>>(edst, deg_i);
    k_scan1<<<SCAN_B, 256, 0, stream>>>(deg_i, partial);
    k_scan2<<<1, 256, 0, stream>>>(partial, row_ptr);
    k_scan3<<<SCAN_B, 256, 0, stream>>>(deg_i, partial, row_ptr, cursor);
    k_scatter<<<(N_EDGES + 255) / 256, 256, 0, stream>>>(esrc, edst, eattr, cursor, s_src, s_attr);
    {
        dim3 g1(512, 3);
        k_wprep<<<g1, 128, 0, stream>>>(msg_w1, upd_w1, upd_w2, W1t, U1t, U2t);
        dim3 g2(HID + 1, 3);
        k_small<<<g2, HID, 0, stream>>>(msg_w2, upd_w1, msg_b2, W2Ut, b2u);
    }

    const int nblk = NPAD / 64;
    // embed + layer-0 pre
    k_embed_pre<<<nblk, 256, 0, stream>>>(z, embed, W1t, msg_b1, h16, P0, Q0);

    bf16* Pa = P0; bf16* Qa = Q0; bf16* Pb = P1; bf16* Qb = Q1;
    for (int l = 0; l < 3; ++l) {
        const float* w1last = msg_w1 + (size_t)l * 257 * HID + 256 * HID;
        const bf16* U1l  = U1t  + (size_t)l * HID * HID;
        const bf16* W2Ul = W2Ut + (size_t)l * HID * HID;
        const bf16* U2l  = U2t  + (size_t)l * HID * HID;
        if (l < 2) {
            k_layer<1><<<nblk, 256, 0, stream>>>(
                h16, Pa, Qa, row_ptr, s_src, s_attr, w1last,
                U1l, W2Ul, upd_b1 + (size_t)l * HID, b2u + l * HID,
                U2l, upd_b2 + (size_t)l * HID,
                W1t + (size_t)(l + 1) * 256 * HID, msg_b1 + (size_t)(l + 1) * HID, Pb, Qb);
            bf16* tp = Pa; Pa = Pb; Pb = tp;
            bf16* tq = Qa; Qa = Qb; Qb = tq;
        } else {
            k_layer<0><<<nblk, 256, 0, stream>>>(
                h16, Pa, Qa, row_ptr, s_src, s_attr, w1last,
                U1l, W2Ul, upd_b1 + (size_t)l * HID, b2u + l * HID,
                U2l, upd_b2 + (size_t)l * HID,
                nullptr, nullptr, nullptr, nullptr);
        }
    }
    hipMemsetAsync(pooled, 0, NUM_GRAPHS * HID * sizeof(float), stream);
    k_pool<<<nblk, 256, 0, stream>>>(h16, batch, pooled);
    k_head<<<NUM_GRAPHS, 128, 0, stream>>>(pooled, batch, head_w1, head_b1, head_w2, head_b2, out);
}